// Round 1
// baseline (1463.555 us; speedup 1.0000x reference)
//
#include <hip/hip_runtime.h>

#define DEV __device__ __forceinline__

typedef short bf16x8 __attribute__((ext_vector_type(8)));
typedef float f32x4 __attribute__((ext_vector_type(4)));

// ---------- helpers ----------
DEV unsigned short f2b(float f) {               // fp32 -> bf16 RNE
    unsigned u = __float_as_uint(f);
    u += 0x7fffu + ((u >> 16) & 1u);
    return (unsigned short)(u >> 16);
}

DEV void async_cp16(const void* g, void* l) {   // global -> LDS, 16B/lane
    __builtin_amdgcn_global_load_lds(
        (const __attribute__((address_space(1))) unsigned int*)g,
        (__attribute__((address_space(3))) unsigned int*)l, 16, 0, 0);
}

DEV float quad_sum(float x) {                   // sum over 4-lane quad via DPP
    x += __int_as_float(__builtin_amdgcn_update_dpp(0, __float_as_int(x), 0xB1, 0xF, 0xF, true));
    x += __int_as_float(__builtin_amdgcn_update_dpp(0, __float_as_int(x), 0x4E, 0xF, 0xF, true));
    return x;
}

// ---------- transpose + cast: in f32 [K][N] -> out bf16 [Npad][K], rows >= N zero ----------
__global__ __launch_bounds__(256) void transpose_cast_k(
    const float* __restrict__ in, unsigned short* __restrict__ out, int K, int N)
{
    __shared__ float tile[32][33];
    const int k0 = blockIdx.x * 32, n0 = blockIdx.y * 32;
    const int tx = threadIdx.x & 31, ty = threadIdx.x >> 5;   // ty 0..7
#pragma unroll
    for (int i = 0; i < 32; i += 8) {
        int n = n0 + tx;
        tile[ty + i][tx] = (n < N) ? in[(size_t)(k0 + ty + i) * N + n] : 0.0f;
    }
    __syncthreads();
#pragma unroll
    for (int i = 0; i < 32; i += 8) {
        out[(size_t)(n0 + ty + i) * K + (k0 + tx)] = f2b(tile[tx][ty + i]);
    }
}

// ---------- concat bias [bq|bk|bv|bbeta|0pad] -> 3200 ----------
__global__ void build_bias_k(const float* __restrict__ bq, const float* __restrict__ bk,
                             const float* __restrict__ bv, const float* __restrict__ bb,
                             float* __restrict__ outb)
{
    int i = blockIdx.x * 256 + threadIdx.x;
    if (i >= 3200) return;
    float v = 0.f;
    if (i < 1024)      v = bq[i];
    else if (i < 2048) v = bk[i - 1024];
    else if (i < 3072) v = bv[i - 2048];
    else if (i < 3088) v = bb[i - 3072];
    outb[i] = v;
}

// ---------- rmsnorm (rows of 1024) + cast to bf16 ----------
__global__ __launch_bounds__(256) void rmsnorm_cast_k(
    const float* __restrict__ x, const float* __restrict__ scale,
    unsigned short* __restrict__ out)
{
    const int row = blockIdx.x;
    const int t = threadIdx.x;
    const float4 v = *(const float4*)(x + (size_t)row * 1024 + t * 4);
    float ss = v.x * v.x + v.y * v.y + v.z * v.z + v.w * v.w;
#pragma unroll
    for (int off = 1; off < 64; off <<= 1) ss += __shfl_xor(ss, off);
    __shared__ float wsum[4];
    if ((t & 63) == 0) wsum[t >> 6] = ss;
    __syncthreads();
    const float tot = wsum[0] + wsum[1] + wsum[2] + wsum[3];
    const float inv = rsqrtf(tot * (1.0f / 1024.0f) + 1e-6f);
    const float4 sc = *(const float4*)(scale + t * 4);
    unsigned int lo = (unsigned)f2b(v.x * inv * sc.x) | ((unsigned)f2b(v.y * inv * sc.y) << 16);
    unsigned int hi = (unsigned)f2b(v.z * inv * sc.z) | ((unsigned)f2b(v.w * inv * sc.w) << 16);
    uint2 pkd; pkd.x = lo; pkd.y = hi;
    *(uint2*)(out + (size_t)row * 1024 + t * 4) = pkd;
}

// ---------- GEMM: C[M,N] = A[M,K](bf16) * BT[N,K](bf16)^T, m97 structure ----------
// MODE 0: C=f32, +bias          MODE 1: C=f32, +bias+add       MODE 2: C=bf16, gelu(+bias)
template <int MODE>
__global__ __launch_bounds__(256) void gemm_bt(
    const unsigned short* __restrict__ A, const unsigned short* __restrict__ BT,
    const float* __restrict__ bias, const float* __restrict__ add,
    void* __restrict__ Cout, int N, int K)
{
    __shared__ unsigned short As[128 * 32];
    __shared__ unsigned short Bs[128 * 32];
    const int tid = threadIdx.x;
    const int wid = tid >> 6;
    const int lane = tid & 63;
    const int m0 = blockIdx.x * 128;
    const int n0 = blockIdx.y * 128;

    const int lrow = lane >> 2;         // 0..15
    const int lkw = (lane & 3) * 8;     // ushort offset within 32-wide k row

    const unsigned short* Ag0 = A + (size_t)(m0 + wid * 16 + lrow) * K + lkw;
    const unsigned short* Ag1 = A + (size_t)(m0 + wid * 16 + 64 + lrow) * K + lkw;
    const unsigned short* Bg0 = BT + (size_t)(n0 + wid * 16 + lrow) * K + lkw;
    const unsigned short* Bg1 = BT + (size_t)(n0 + wid * 16 + 64 + lrow) * K + lkw;
    unsigned short* As0 = &As[(wid * 16) * 32];
    unsigned short* As1 = &As[(wid * 16 + 64) * 32];
    unsigned short* Bs0 = &Bs[(wid * 16) * 32];
    unsigned short* Bs1 = &Bs[(wid * 16 + 64) * 32];

    f32x4 acc[4][4];
#pragma unroll
    for (int i = 0; i < 4; i++)
#pragma unroll
        for (int j = 0; j < 4; j++) acc[i][j] = (f32x4)0.f;

    const int wm = (wid & 1) * 64;
    const int wn = (wid >> 1) * 64;
    const int l16 = lane & 15;
    const int koff = (lane >> 4) * 8;

    for (int k0 = 0; k0 < K; k0 += 32) {
        async_cp16(Ag0 + k0, As0);
        async_cp16(Ag1 + k0, As1);
        async_cp16(Bg0 + k0, Bs0);
        async_cp16(Bg1 + k0, Bs1);
        __syncthreads();   // drains vmcnt before barrier -> LDS valid
        bf16x8 af[4], bfv[4];
#pragma unroll
        for (int i = 0; i < 4; i++) af[i] = *(const bf16x8*)&As[(wm + i * 16 + l16) * 32 + koff];
#pragma unroll
        for (int j = 0; j < 4; j++) bfv[j] = *(const bf16x8*)&Bs[(wn + j * 16 + l16) * 32 + koff];
#pragma unroll
        for (int i = 0; i < 4; i++)
#pragma unroll
            for (int j = 0; j < 4; j++)
                acc[i][j] = __builtin_amdgcn_mfma_f32_16x16x32_bf16(af[i], bfv[j], acc[i][j], 0, 0, 0);
        __syncthreads();
    }

#pragma unroll
    for (int j = 0; j < 4; j++) {
        const int cg = n0 + wn + j * 16 + l16;
        const float bv = bias[cg];
#pragma unroll
        for (int i = 0; i < 4; i++) {
            const int rg0 = m0 + wm + i * 16 + (lane >> 4) * 4;
#pragma unroll
            for (int r = 0; r < 4; r++) {
                size_t idx = (size_t)(rg0 + r) * N + cg;
                float v = acc[i][j][r] + bv;
                if (MODE == 1) v += add[idx];
                if (MODE == 2) {
                    float u = v;
                    float t = tanhf(0.7978845608028654f * (u + 0.044715f * u * u * u));
                    ((unsigned short*)Cout)[idx] = f2b(0.5f * u * (1.f + t));
                } else {
                    ((float*)Cout)[idx] = v;
                }
            }
        }
    }
}

// ---------- GDN delta-rule scan ----------
// qkv layout per row (stride 3200): [q 0..1023 | k 1024..2047 | v 2048..3071 | blogit 3072..3087 | pad]
// one block per (b,h); thread t: d = t>>2 owns row d of S, c = t&3 owns 16-col chunk.
__global__ __launch_bounds__(256, 1) void gdn_scan(
    const float* __restrict__ qkv, unsigned short* __restrict__ attn)
{
    const int b = blockIdx.x >> 4, h = blockIdx.x & 15;
    const int t = threadIdx.x;
    const int d = t >> 2, c = t & 3;
    const int e0 = c * 16;
    const float* base = qkv + (size_t)b * 2048 * 3200;
    const int qo = h * 64 + e0;
    const int ko = 1024 + h * 64 + e0;
    const int vo = 2048 + h * 64 + d;
    const int bo = 3072 + h;
    unsigned short* arow = attn + (size_t)b * 2048 * 1024 + h * 64 + d;

    float S[16];
#pragma unroll
    for (int j = 0; j < 16; j++) S[j] = 0.f;

    constexpr int PD = 4;   // software-pipeline depth
    float pk[PD][16], pq[PD][16], pv[PD], pb[PD];

    auto load_slot = [&](int slot, int s) {
        const float* r = base + (size_t)s * 3200;
#pragma unroll
        for (int i = 0; i < 4; i++) {
            float4 kv = *(const float4*)(r + ko + i * 4);
            pk[slot][i * 4 + 0] = kv.x; pk[slot][i * 4 + 1] = kv.y;
            pk[slot][i * 4 + 2] = kv.z; pk[slot][i * 4 + 3] = kv.w;
            float4 qv = *(const float4*)(r + qo + i * 4);
            pq[slot][i * 4 + 0] = qv.x; pq[slot][i * 4 + 1] = qv.y;
            pq[slot][i * 4 + 2] = qv.z; pq[slot][i * 4 + 3] = qv.w;
        }
        pv[slot] = r[vo];
        pb[slot] = r[bo];
    };

#pragma unroll
    for (int u = 0; u < PD; u++) load_slot(u, u);

    for (int sb = 0; sb < 2048; sb += PD) {
#pragma unroll
        for (int u = 0; u < PD; ++u) {
            const int s = sb + u;
            // ||k||^2 and S.k (old S) in one pass; fold 1/(||k||+eps) into scale
            float ss0 = 0.f, ss1 = 0.f, dt0 = 0.f, dt1 = 0.f;
#pragma unroll
            for (int j = 0; j < 8; j++) {
                ss0 += pk[u][j] * pk[u][j];
                ss1 += pk[u][8 + j] * pk[u][8 + j];
                dt0 += S[j] * pk[u][j];
                dt1 += S[8 + j] * pk[u][8 + j];
            }
            const float ssq = quad_sum(ss0 + ss1);
            const float dot = quad_sum(dt0 + dt1);
            const float inv = 1.f / (sqrtf(ssq) + 1e-6f);
            const float beta = 1.f / (1.f + __expf(-pb[u]));
            const float coef = beta * (pv[u] - dot * inv) * inv;  // beta*(v - S.kn) applied to kn
#pragma unroll
            for (int j = 0; j < 16; j++) S[j] = fmaf(coef, pk[u][j], S[j]);
            float oo0 = 0.f, oo1 = 0.f;
#pragma unroll
            for (int j = 0; j < 8; j++) { oo0 += S[j] * pq[u][j]; oo1 += S[8 + j] * pq[u][8 + j]; }
            const float o = quad_sum(oo0 + oo1);
            if (c == 0) arow[(size_t)s * 1024] = f2b(o);
            if (s + PD < 2048) load_slot(u, s + PD);
        }
    }
}

// ---------- workspace layout ----------
static constexpr size_t OFF_H     = 0;                         // 16,777,216  h / h2 bf16
static constexpr size_t OFF_WQKVT = OFF_H + 16777216;          //  6,553,600  [3200][1024] bf16
static constexpr size_t OFF_WOT   = OFF_WQKVT + 6553600;       //  2,097,152
static constexpr size_t OFF_W1T   = OFF_WOT + 2097152;         //  8,388,608  [4096][1024]
static constexpr size_t OFF_W2T   = OFF_W1T + 8388608;         //  8,388,608  [1024][4096]
static constexpr size_t OFF_BIAS  = OFF_W2T + 8388608;         //     16,384  (3200 f32)
static constexpr size_t OFF_QKV   = OFF_BIAS + 16384;          // 104,857,600 f32 (reused as g bf16)
static constexpr size_t OFF_ATTN  = OFF_QKV + 104857600;       // 16,777,216  bf16
static constexpr size_t OFF_Y1    = OFF_ATTN + 16777216;       // 33,554,432  f32

extern "C" void kernel_launch(void* const* d_in, const int* in_sizes, int n_in,
                              void* d_out, int out_size, void* d_ws, size_t ws_size,
                              hipStream_t stream)
{
    const float* x     = (const float*)d_in[0];
    const float* wq    = (const float*)d_in[1];
    const float* bq    = (const float*)d_in[2];
    const float* wk    = (const float*)d_in[3];
    const float* bk    = (const float*)d_in[4];
    const float* wv    = (const float*)d_in[5];
    const float* bv    = (const float*)d_in[6];
    const float* wbeta = (const float*)d_in[7];
    const float* bbeta = (const float*)d_in[8];
    const float* wo    = (const float*)d_in[9];
    const float* bo    = (const float*)d_in[10];
    const float* w1    = (const float*)d_in[11];
    const float* b1    = (const float*)d_in[12];
    const float* w2    = (const float*)d_in[13];
    const float* b2    = (const float*)d_in[14];
    const float* ln1   = (const float*)d_in[15];
    const float* ln2   = (const float*)d_in[16];

    char* ws = (char*)d_ws;
    unsigned short* hbuf  = (unsigned short*)(ws + OFF_H);
    unsigned short* wqkvT = (unsigned short*)(ws + OFF_WQKVT);
    unsigned short* woT   = (unsigned short*)(ws + OFF_WOT);
    unsigned short* w1T   = (unsigned short*)(ws + OFF_W1T);
    unsigned short* w2T   = (unsigned short*)(ws + OFF_W2T);
    float*          biasc = (float*)(ws + OFF_BIAS);
    float*          qkv   = (float*)(ws + OFF_QKV);
    unsigned short* gbuf  = (unsigned short*)(ws + OFF_QKV);   // reuse after scan
    unsigned short* attn  = (unsigned short*)(ws + OFF_ATTN);
    float*          y1    = (float*)(ws + OFF_Y1);
    float*          out   = (float*)d_out;

    // weight transpose+cast (B^T bf16 operands)
    transpose_cast_k<<<dim3(32, 32), 256, 0, stream>>>(wq, wqkvT,               1024, 1024);
    transpose_cast_k<<<dim3(32, 32), 256, 0, stream>>>(wk, wqkvT + 1024 * 1024, 1024, 1024);
    transpose_cast_k<<<dim3(32, 32), 256, 0, stream>>>(wv, wqkvT + 2048 * 1024, 1024, 1024);
    transpose_cast_k<<<dim3(32, 4),  256, 0, stream>>>(wbeta, wqkvT + 3072 * 1024, 1024, 16); // pad->128 rows
    transpose_cast_k<<<dim3(32, 32), 256, 0, stream>>>(wo, woT, 1024, 1024);
    transpose_cast_k<<<dim3(32, 128), 256, 0, stream>>>(w1, w1T, 1024, 4096);
    transpose_cast_k<<<dim3(128, 32), 256, 0, stream>>>(w2, w2T, 4096, 1024);
    build_bias_k<<<13, 256, 0, stream>>>(bq, bk, bv, bbeta, biasc);

    // layer
    rmsnorm_cast_k<<<8192, 256, 0, stream>>>(x, ln1, hbuf);
    gemm_bt<0><<<dim3(64, 25), 256, 0, stream>>>(hbuf, wqkvT, biasc, nullptr, qkv, 3200, 1024);
    gdn_scan<<<64, 256, 0, stream>>>(qkv, attn);
    gemm_bt<1><<<dim3(64, 8), 256, 0, stream>>>(attn, woT, bo, x, y1, 1024, 1024);
    rmsnorm_cast_k<<<8192, 256, 0, stream>>>(y1, ln2, hbuf);
    gemm_bt<2><<<dim3(64, 32), 256, 0, stream>>>(hbuf, w1T, b1, nullptr, gbuf, 4096, 1024);
    gemm_bt<1><<<dim3(64, 8), 256, 0, stream>>>(gbuf, w2T, b2, y1, out, 1024, 4096);
}

// Round 2
// 814.442 us; speedup vs baseline: 1.7970x; 1.7970x over previous
//
#include <hip/hip_runtime.h>

#define DEV __device__ __forceinline__

typedef short bf16x8 __attribute__((ext_vector_type(8)));
typedef float f32x4 __attribute__((ext_vector_type(4)));
typedef unsigned int uint;

// ---------- helpers ----------
DEV unsigned short f2b(float f) {               // fp32 -> bf16 RNE
    uint u = __float_as_uint(f);
    u += 0x7fffu + ((u >> 16) & 1u);
    return (unsigned short)(u >> 16);
}
DEV uint packbf2(float a, float b) { return (uint)f2b(a) | ((uint)f2b(b) << 16); }
DEV float b2f(unsigned short s) { return __uint_as_float(((uint)s) << 16); }
DEV float b2f_lo(uint u) { return __uint_as_float(u << 16); }
DEV float b2f_hi(uint u) { return __uint_as_float(u & 0xffff0000u); }

DEV void async_cp16(const void* g, void* l) {   // global -> LDS, 16B/lane
    __builtin_amdgcn_global_load_lds(
        (const __attribute__((address_space(1))) unsigned int*)g,
        (__attribute__((address_space(3))) unsigned int*)l, 16, 0, 0);
}

DEV float quad_sum(float x) {                   // sum over 4-lane quad via DPP
    x += __int_as_float(__builtin_amdgcn_update_dpp(0, __float_as_int(x), 0xB1, 0xF, 0xF, true));
    x += __int_as_float(__builtin_amdgcn_update_dpp(0, __float_as_int(x), 0x4E, 0xF, 0xF, true));
    return x;
}

// ---------- transpose + cast: in f32 [K][N] -> out bf16 [Npad][K], rows >= N zero ----------
__global__ __launch_bounds__(256) void transpose_cast_k(
    const float* __restrict__ in, unsigned short* __restrict__ out, int K, int N)
{
    __shared__ float tile[32][33];
    const int k0 = blockIdx.x * 32, n0 = blockIdx.y * 32;
    const int tx = threadIdx.x & 31, ty = threadIdx.x >> 5;   // ty 0..7
#pragma unroll
    for (int i = 0; i < 32; i += 8) {
        int n = n0 + tx;
        tile[ty + i][tx] = (n < N) ? in[(size_t)(k0 + ty + i) * N + n] : 0.0f;
    }
    __syncthreads();
#pragma unroll
    for (int i = 0; i < 32; i += 8) {
        out[(size_t)(n0 + ty + i) * K + (k0 + tx)] = f2b(tile[tx][ty + i]);
    }
}

// ---------- concat bias [bq|bk|bv|bbeta|0pad] -> 3200 ----------
__global__ void build_bias_k(const float* __restrict__ bq, const float* __restrict__ bk,
                             const float* __restrict__ bv, const float* __restrict__ bb,
                             float* __restrict__ outb)
{
    int i = blockIdx.x * 256 + threadIdx.x;
    if (i >= 3200) return;
    float v = 0.f;
    if (i < 1024)      v = bq[i];
    else if (i < 2048) v = bk[i - 1024];
    else if (i < 3072) v = bv[i - 2048];
    else if (i < 3088) v = bb[i - 3072];
    outb[i] = v;
}

// ---------- rmsnorm (rows of 1024) + cast to bf16 ----------
__global__ __launch_bounds__(256) void rmsnorm_cast_k(
    const float* __restrict__ x, const float* __restrict__ scale,
    unsigned short* __restrict__ out)
{
    const int row = blockIdx.x;
    const int t = threadIdx.x;
    const float4 v = *(const float4*)(x + (size_t)row * 1024 + t * 4);
    float ss = v.x * v.x + v.y * v.y + v.z * v.z + v.w * v.w;
#pragma unroll
    for (int off = 1; off < 64; off <<= 1) ss += __shfl_xor(ss, off);
    __shared__ float wsum[4];
    if ((t & 63) == 0) wsum[t >> 6] = ss;
    __syncthreads();
    const float tot = wsum[0] + wsum[1] + wsum[2] + wsum[3];
    const float inv = rsqrtf(tot * (1.0f / 1024.0f) + 1e-6f);
    const float4 sc = *(const float4*)(scale + t * 4);
    uint lo = (uint)f2b(v.x * inv * sc.x) | ((uint)f2b(v.y * inv * sc.y) << 16);
    uint hi = (uint)f2b(v.z * inv * sc.z) | ((uint)f2b(v.w * inv * sc.w) << 16);
    uint2 pkd; pkd.x = lo; pkd.y = hi;
    *(uint2*)(out + (size_t)row * 1024 + t * 4) = pkd;
}

// ---------- GEMM: C[M,N] = A[M,K](bf16) * BT[N,K](bf16)^T, m97 structure ----------
// MODE 0: C=f32, +bias          MODE 1: C=f32, +bias+add       MODE 2: C=bf16, gelu(+bias)
template <int MODE>
__global__ __launch_bounds__(256) void gemm_bt(
    const unsigned short* __restrict__ A, const unsigned short* __restrict__ BT,
    const float* __restrict__ bias, const float* __restrict__ add,
    void* __restrict__ Cout, int N, int K)
{
    __shared__ unsigned short As[128 * 32];
    __shared__ unsigned short Bs[128 * 32];
    const int tid = threadIdx.x;
    const int wid = tid >> 6;
    const int lane = tid & 63;
    const int m0 = blockIdx.x * 128;
    const int n0 = blockIdx.y * 128;

    const int lrow = lane >> 2;         // 0..15
    const int lkw = (lane & 3) * 8;     // ushort offset within 32-wide k row

    const unsigned short* Ag0 = A + (size_t)(m0 + wid * 16 + lrow) * K + lkw;
    const unsigned short* Ag1 = A + (size_t)(m0 + wid * 16 + 64 + lrow) * K + lkw;
    const unsigned short* Bg0 = BT + (size_t)(n0 + wid * 16 + lrow) * K + lkw;
    const unsigned short* Bg1 = BT + (size_t)(n0 + wid * 16 + 64 + lrow) * K + lkw;
    unsigned short* As0 = &As[(wid * 16) * 32];
    unsigned short* As1 = &As[(wid * 16 + 64) * 32];
    unsigned short* Bs0 = &Bs[(wid * 16) * 32];
    unsigned short* Bs1 = &Bs[(wid * 16 + 64) * 32];

    f32x4 acc[4][4];
#pragma unroll
    for (int i = 0; i < 4; i++)
#pragma unroll
        for (int j = 0; j < 4; j++) acc[i][j] = (f32x4)0.f;

    const int wm = (wid & 1) * 64;
    const int wn = (wid >> 1) * 64;
    const int l16 = lane & 15;
    const int koff = (lane >> 4) * 8;

    for (int k0 = 0; k0 < K; k0 += 32) {
        async_cp16(Ag0 + k0, As0);
        async_cp16(Ag1 + k0, As1);
        async_cp16(Bg0 + k0, Bs0);
        async_cp16(Bg1 + k0, Bs1);
        __syncthreads();
        bf16x8 af[4], bfv[4];
#pragma unroll
        for (int i = 0; i < 4; i++) af[i] = *(const bf16x8*)&As[(wm + i * 16 + l16) * 32 + koff];
#pragma unroll
        for (int j = 0; j < 4; j++) bfv[j] = *(const bf16x8*)&Bs[(wn + j * 16 + l16) * 32 + koff];
#pragma unroll
        for (int i = 0; i < 4; i++)
#pragma unroll
            for (int j = 0; j < 4; j++)
                acc[i][j] = __builtin_amdgcn_mfma_f32_16x16x32_bf16(af[i], bfv[j], acc[i][j], 0, 0, 0);
        __syncthreads();
    }

#pragma unroll
    for (int j = 0; j < 4; j++) {
        const int cg = n0 + wn + j * 16 + l16;
        const float bv = bias[cg];
#pragma unroll
        for (int i = 0; i < 4; i++) {
            const int rg0 = m0 + wm + i * 16 + (lane >> 4) * 4;
#pragma unroll
            for (int r = 0; r < 4; r++) {
                size_t idx = (size_t)(rg0 + r) * N + cg;
                float v = acc[i][j][r] + bv;
                if (MODE == 1) v += add[idx];
                if (MODE == 2) {
                    float u = v;
                    float t = tanhf(0.7978845608028654f * (u + 0.044715f * u * u * u));
                    ((unsigned short*)Cout)[idx] = f2b(0.5f * u * (1.f + t));
                } else {
                    ((float*)Cout)[idx] = v;
                }
            }
        }
    }
}

// =====================================================================
// Chunked WY delta-rule scan, chunk L=64.
//   A = strictly_lower(diag(beta) Kn Kn^T)
//   (I+A) W = diag(beta) Kn      (I+A) Z = diag(beta) V
//   per chunk (sequential): Y = Z - W S_c^T ; S = S_c + Y^T Kn
//   outputs (parallel):     O = Q S_c^T + tril(Q Kn^T, incl diag) Y
// =====================================================================

// ---------- prep: per (bh, chunk): normalize k in place, build A, solve W,Z ----------
__global__ __launch_bounds__(256) void gdn_prep(
    float* __restrict__ qkv, unsigned short* __restrict__ Wg, unsigned short* __restrict__ Zg)
{
    const int chunk = blockIdx.x, bh = blockIdx.y;
    const int b = bh >> 4, h = bh & 15;
    __shared__ float Ks[64 * 68];
    __shared__ float Ws[64 * 65];
    __shared__ float Zs[64 * 65];
    __shared__ float Asl[64 * 65];
    __shared__ float bs[64];
    const int tid = threadIdx.x;
    const int t = tid >> 2, c = tid & 3;
    float* rowp = qkv + (size_t)(b * 2048 + chunk * 64 + t) * 3200;

    // phase 1a: load k row slice, row norm, write Kn to LDS + back to global
    float kn[16];
    float ss = 0.f;
#pragma unroll
    for (int i = 0; i < 4; i++) {
        float4 kv = *(const float4*)(rowp + 1024 + h * 64 + 16 * c + 4 * i);
        kn[4 * i + 0] = kv.x; kn[4 * i + 1] = kv.y; kn[4 * i + 2] = kv.z; kn[4 * i + 3] = kv.w;
        ss += kv.x * kv.x + kv.y * kv.y + kv.z * kv.z + kv.w * kv.w;
    }
    ss = quad_sum(ss);
    const float inv = 1.f / (sqrtf(ss) + 1e-6f);
#pragma unroll
    for (int j = 0; j < 16; j++) kn[j] *= inv;
#pragma unroll
    for (int i = 0; i < 4; i++) {
        float4 kv; kv.x = kn[4 * i]; kv.y = kn[4 * i + 1]; kv.z = kn[4 * i + 2]; kv.w = kn[4 * i + 3];
        *(float4*)(&Ks[t * 68 + 16 * c + 4 * i]) = kv;              // aligned: all idx mult of 4
        *(float4*)(rowp + 1024 + h * 64 + 16 * c + 4 * i) = kv;     // Kn in place
    }
    if (c == 0) bs[t] = 1.f / (1.f + __expf(-rowp[3072 + h]));
    __syncthreads();

    // phase 1b: RHS: W = beta*Kn, Z = beta*V
    const float beta = bs[t];
#pragma unroll
    for (int j = 0; j < 16; j++) Ws[t * 65 + 16 * c + j] = beta * kn[j];
#pragma unroll
    for (int i = 0; i < 4; i++) {
        float4 vv = *(const float4*)(rowp + 2048 + h * 64 + 16 * c + 4 * i);
        Zs[t * 65 + 16 * c + 4 * i + 0] = beta * vv.x;
        Zs[t * 65 + 16 * c + 4 * i + 1] = beta * vv.y;
        Zs[t * 65 + 16 * c + 4 * i + 2] = beta * vv.z;
        Zs[t * 65 + 16 * c + 4 * i + 3] = beta * vv.w;
    }
    __syncthreads();

    // phase 2: A = strictly_lower(diag(beta) Kn Kn^T); 4x4 tile per thread
    {
        const int tt = tid >> 4, sx = tid & 15;
        float dm[4][4];
#pragma unroll
        for (int i = 0; i < 4; i++)
#pragma unroll
            for (int j = 0; j < 4; j++) dm[i][j] = 0.f;
        for (int d = 0; d < 64; d++) {
            float kt[4], ksv[4];
#pragma unroll
            for (int i = 0; i < 4; i++) kt[i] = Ks[(4 * tt + i) * 68 + d];
#pragma unroll
            for (int j = 0; j < 4; j++) ksv[j] = Ks[(4 * sx + j) * 68 + d];
#pragma unroll
            for (int i = 0; i < 4; i++)
#pragma unroll
                for (int j = 0; j < 4; j++) dm[i][j] += kt[i] * ksv[j];
        }
#pragma unroll
        for (int i = 0; i < 4; i++)
#pragma unroll
            for (int j = 0; j < 4; j++) {
                int T = 4 * tt + i, S_ = 4 * sx + j;
                Asl[T * 65 + S_] = (S_ < T) ? bs[T] * dm[i][j] : 0.f;
            }
    }
    __syncthreads();

    // phase 3: blocked forward substitution (I+A)X = RHS for W and Z
    {
        const int wid = tid >> 6, lane = tid & 63;  // lane = d
        for (int qi = 0; qi < 4; qi++) {
            if (qi > 0) {
                const int tb = qi * 16 + wid * 4;
                float aw[4], az[4];
#pragma unroll
                for (int i = 0; i < 4; i++) { aw[i] = Ws[(tb + i) * 65 + lane]; az[i] = Zs[(tb + i) * 65 + lane]; }
                for (int s = 0; s < qi * 16; s++) {
                    float wsv = Ws[s * 65 + lane], zsv = Zs[s * 65 + lane];
#pragma unroll
                    for (int i = 0; i < 4; i++) {
                        float a = Asl[(tb + i) * 65 + s];
                        aw[i] -= a * wsv; az[i] -= a * zsv;
                    }
                }
#pragma unroll
                for (int i = 0; i < 4; i++) { Ws[(tb + i) * 65 + lane] = aw[i]; Zs[(tb + i) * 65 + lane] = az[i]; }
            }
            __syncthreads();
            if (wid == 0) {
                for (int T = qi * 16; T < qi * 16 + 16; T++) {
                    float a_ = Ws[T * 65 + lane];
                    for (int s = qi * 16; s < T; s++) a_ -= Asl[T * 65 + s] * Ws[s * 65 + lane];
                    Ws[T * 65 + lane] = a_;
                }
            } else if (wid == 1) {
                for (int T = qi * 16; T < qi * 16 + 16; T++) {
                    float a_ = Zs[T * 65 + lane];
                    for (int s = qi * 16; s < T; s++) a_ -= Asl[T * 65 + s] * Zs[s * 65 + lane];
                    Zs[T * 65 + lane] = a_;
                }
            }
            __syncthreads();
        }
    }

    // phase 4: write W, Z (bf16)
    {
        size_t base = ((size_t)bh * 2048 + chunk * 64 + t) * 64 + 16 * c;
        uint wpk[8], zpk[8];
#pragma unroll
        for (int p = 0; p < 8; p++) {
            wpk[p] = packbf2(Ws[t * 65 + 16 * c + 2 * p], Ws[t * 65 + 16 * c + 2 * p + 1]);
            zpk[p] = packbf2(Zs[t * 65 + 16 * c + 2 * p], Zs[t * 65 + 16 * c + 2 * p + 1]);
        }
        uint4 w0; w0.x = wpk[0]; w0.y = wpk[1]; w0.z = wpk[2]; w0.w = wpk[3];
        uint4 w1; w1.x = wpk[4]; w1.y = wpk[5]; w1.z = wpk[6]; w1.w = wpk[7];
        *(uint4*)(Wg + base) = w0; *(uint4*)(Wg + base + 8) = w1;
        uint4 z0; z0.x = zpk[0]; z0.y = zpk[1]; z0.z = zpk[2]; z0.w = zpk[3];
        uint4 z1; z1.x = zpk[4]; z1.y = zpk[5]; z1.z = zpk[6]; z1.w = zpk[7];
        *(uint4*)(Zg + base) = z0; *(uint4*)(Zg + base + 8) = z1;
    }
}

// ---------- prop: sequential over chunks; block = (jq, bh); Y = Z - W S^T; S += Y^T Kn ----------
__global__ __launch_bounds__(256) void gdn_prop(
    const float* __restrict__ qkv, const unsigned short* __restrict__ Wg,
    unsigned short* __restrict__ Zg /* in Z, out Y */, unsigned short* __restrict__ Sall)
{
    const int jq = blockIdx.x, bh = blockIdx.y;
    const int b = bh >> 4, h = bh & 15;
    __shared__ float Wf[64 * 68];
    __shared__ float Kf[64 * 68];
    __shared__ float Sloc[16 * 68];
    __shared__ float Ys[64 * 17];
    const int tid = threadIdx.x;
    const int t = tid >> 2, c = tid & 3;
    const int jj = tid & 3;           // (a) map: thread (t, jj) -> T1[t][4jj..+3]
    const int jl = tid >> 4, dg = tid & 15;  // (c) map

    for (int i = tid; i < 16 * 68; i += 256) Sloc[i] = 0.f;
    __syncthreads();

    for (int ch = 0; ch < 32; ch++) {
        // stage W (bf16->f32) and Kn (f32)
        const unsigned short* wrow = Wg + ((size_t)bh * 2048 + ch * 64 + t) * 64 + 16 * c;
        uint4 wa = *(const uint4*)wrow;
        uint4 wb = *(const uint4*)(wrow + 8);
        const float* krow = qkv + (size_t)(b * 2048 + ch * 64 + t) * 3200 + 1024 + h * 64 + 16 * c;
        float4 k0 = *(const float4*)(krow + 0);
        float4 k1 = *(const float4*)(krow + 4);
        float4 k2 = *(const float4*)(krow + 8);
        float4 k3 = *(const float4*)(krow + 12);
        // Z slice for this block's j-range (used after (a))
        unsigned short* zp = Zg + ((size_t)bh * 2048 + ch * 64 + (tid >> 2)) * 64 + jq * 16 + jj * 4;
        uint2 zl = *(const uint2*)zp;
        // snapshot chunk-start S -> Sall (bf16)
        {
            float4 sv = *(const float4*)&Sloc[jl * 68 + 4 * dg];
            uint2 sp; sp.x = packbf2(sv.x, sv.y); sp.y = packbf2(sv.z, sv.w);
            *(uint2*)(Sall + ((size_t)bh * 32 + ch) * 4096 + (jq * 16 + jl) * 64 + 4 * dg) = sp;
        }
        {
            float4 wv0; wv0.x = b2f_lo(wa.x); wv0.y = b2f_hi(wa.x); wv0.z = b2f_lo(wa.y); wv0.w = b2f_hi(wa.y);
            float4 wv1; wv1.x = b2f_lo(wa.z); wv1.y = b2f_hi(wa.z); wv1.z = b2f_lo(wa.w); wv1.w = b2f_hi(wa.w);
            float4 wv2; wv2.x = b2f_lo(wb.x); wv2.y = b2f_hi(wb.x); wv2.z = b2f_lo(wb.y); wv2.w = b2f_hi(wb.y);
            float4 wv3; wv3.x = b2f_lo(wb.z); wv3.y = b2f_hi(wb.z); wv3.z = b2f_lo(wb.w); wv3.w = b2f_hi(wb.w);
            *(float4*)&Wf[t * 68 + 16 * c + 0]  = wv0;
            *(float4*)&Wf[t * 68 + 16 * c + 4]  = wv1;
            *(float4*)&Wf[t * 68 + 16 * c + 8]  = wv2;
            *(float4*)&Wf[t * 68 + 16 * c + 12] = wv3;
            *(float4*)&Kf[t * 68 + 16 * c + 0]  = k0;
            *(float4*)&Kf[t * 68 + 16 * c + 4]  = k1;
            *(float4*)&Kf[t * 68 + 16 * c + 8]  = k2;
            *(float4*)&Kf[t * 68 + 16 * c + 12] = k3;
        }
        __syncthreads();

        // (a) T1[t][j] = sum_d W[t][d] * S[j][d]  (j = 4jj..+3 local)
        float acc0 = 0.f, acc1 = 0.f, acc2 = 0.f, acc3 = 0.f;
        for (int d = 0; d < 64; d++) {
            float wv = Wf[t * 68 + d];
            acc0 += wv * Sloc[(4 * jj + 0) * 68 + d];
            acc1 += wv * Sloc[(4 * jj + 1) * 68 + d];
            acc2 += wv * Sloc[(4 * jj + 2) * 68 + d];
            acc3 += wv * Sloc[(4 * jj + 3) * 68 + d];
        }
        // Y = Z - T1 ; write LDS + global (overwrite Z)
        float y0 = b2f_lo(zl.x) - acc0;
        float y1 = b2f_hi(zl.x) - acc1;
        float y2 = b2f_lo(zl.y) - acc2;
        float y3 = b2f_hi(zl.y) - acc3;
        Ys[t * 17 + 4 * jj + 0] = y0;
        Ys[t * 17 + 4 * jj + 1] = y1;
        Ys[t * 17 + 4 * jj + 2] = y2;
        Ys[t * 17 + 4 * jj + 3] = y3;
        uint2 yp; yp.x = packbf2(y0, y1); yp.y = packbf2(y2, y3);
        *(uint2*)zp = yp;
        __syncthreads();

        // (c) S[jl][d] += sum_t Y[t][jl] * Kn[t][d]
        {
            f32x4 sacc = *(const f32x4*)&Sloc[jl * 68 + 4 * dg];
            for (int tt = 0; tt < 64; tt++) {
                float yv = Ys[tt * 17 + jl];
                f32x4 kv = *(const f32x4*)&Kf[tt * 68 + 4 * dg];
                sacc += yv * kv;
            }
            *(f32x4*)&Sloc[jl * 68 + 4 * dg] = sacc;
        }
        __syncthreads();
    }
}

// ---------- output: per (bh, chunk): O = Q S_c^T + tril(Q Kn^T) Y ----------
__global__ __launch_bounds__(256) void gdn_out(
    const float* __restrict__ qkv, const unsigned short* __restrict__ Yg,
    const unsigned short* __restrict__ Sall, unsigned short* __restrict__ attn)
{
    const int chunk = blockIdx.x, bh = blockIdx.y;
    const int b = bh >> 4, h = bh & 15;
    __shared__ float Qf[64 * 68];
    __shared__ float Sf[64 * 68];
    __shared__ float Ms[64 * 65];
    __shared__ uint Kp[64 * 33];
    __shared__ uint Yp[64 * 34];
    const int tid = threadIdx.x;
    const int t = tid >> 2, c = tid & 3;

    // stage
    {
        const float* rowp = qkv + (size_t)(b * 2048 + chunk * 64 + t) * 3200;
#pragma unroll
        for (int i = 0; i < 4; i++) {
            float4 qv = *(const float4*)(rowp + h * 64 + 16 * c + 4 * i);
            *(float4*)&Qf[t * 68 + 16 * c + 4 * i] = qv;
        }
#pragma unroll
        for (int i = 0; i < 2; i++) {
            float4 ka = *(const float4*)(rowp + 1024 + h * 64 + 16 * c + 8 * i);
            float4 kb = *(const float4*)(rowp + 1024 + h * 64 + 16 * c + 8 * i + 4);
            Kp[t * 33 + 8 * c + 4 * i + 0] = packbf2(ka.x, ka.y);
            Kp[t * 33 + 8 * c + 4 * i + 1] = packbf2(ka.z, ka.w);
            Kp[t * 33 + 8 * c + 4 * i + 2] = packbf2(kb.x, kb.y);
            Kp[t * 33 + 8 * c + 4 * i + 3] = packbf2(kb.z, kb.w);
        }
        const unsigned short* yrow = Yg + ((size_t)bh * 2048 + chunk * 64 + t) * 64 + 16 * c;
        uint4 ya = *(const uint4*)yrow;
        uint4 yb = *(const uint4*)(yrow + 8);
        Yp[t * 34 + 8 * c + 0] = ya.x; Yp[t * 34 + 8 * c + 1] = ya.y;
        Yp[t * 34 + 8 * c + 2] = ya.z; Yp[t * 34 + 8 * c + 3] = ya.w;
        Yp[t * 34 + 8 * c + 4] = yb.x; Yp[t * 34 + 8 * c + 5] = yb.y;
        Yp[t * 34 + 8 * c + 6] = yb.z; Yp[t * 34 + 8 * c + 7] = yb.w;
        const unsigned short* srow = Sall + ((size_t)bh * 32 + chunk) * 4096 + t * 64 + 16 * c; // t = j row
        uint4 sa = *(const uint4*)srow;
        uint4 sb = *(const uint4*)(srow + 8);
        float4 s0; s0.x = b2f_lo(sa.x); s0.y = b2f_hi(sa.x); s0.z = b2f_lo(sa.y); s0.w = b2f_hi(sa.y);
        float4 s1; s1.x = b2f_lo(sa.z); s1.y = b2f_hi(sa.z); s1.z = b2f_lo(sa.w); s1.w = b2f_hi(sa.w);
        float4 s2; s2.x = b2f_lo(sb.x); s2.y = b2f_hi(sb.x); s2.z = b2f_lo(sb.y); s2.w = b2f_hi(sb.y);
        float4 s3; s3.x = b2f_lo(sb.z); s3.y = b2f_hi(sb.z); s3.z = b2f_lo(sb.w); s3.w = b2f_hi(sb.w);
        *(float4*)&Sf[t * 68 + 16 * c + 0]  = s0;
        *(float4*)&Sf[t * 68 + 16 * c + 4]  = s1;
        *(float4*)&Sf[t * 68 + 16 * c + 8]  = s2;
        *(float4*)&Sf[t * 68 + 16 * c + 12] = s3;
    }
    __syncthreads();

    const int tt = tid >> 4, sx = tid & 15;
    // M = tril(Q Kn^T) incl diag
    {
        float dm[4][4];
#pragma unroll
        for (int i = 0; i < 4; i++)
#pragma unroll
            for (int j = 0; j < 4; j++) dm[i][j] = 0.f;
        for (int p = 0; p < 32; p++) {
            float q0[4], q1[4];
#pragma unroll
            for (int i = 0; i < 4; i++) {
                q0[i] = Qf[(4 * tt + i) * 68 + 2 * p];
                q1[i] = Qf[(4 * tt + i) * 68 + 2 * p + 1];
            }
#pragma unroll
            for (int j = 0; j < 4; j++) {
                uint kp = Kp[(4 * sx + j) * 33 + p];
                float kk0 = b2f_lo(kp), kk1 = b2f_hi(kp);
#pragma unroll
                for (int i = 0; i < 4; i++) dm[i][j] += q0[i] * kk0 + q1[i] * kk1;
            }
        }
#pragma unroll
        for (int i = 0; i < 4; i++)
#pragma unroll
            for (int j = 0; j < 4; j++) {
                int T = 4 * tt + i, S_ = 4 * sx + j;
                Ms[T * 65 + S_] = (S_ <= T) ? dm[i][j] : 0.f;
            }
    }
    __syncthreads();

    // O[4t][4j]: part1 Q S^T + part2 M Y
    {
        float o[4][4];
#pragma unroll
        for (int i = 0; i < 4; i++)
#pragma unroll
            for (int j = 0; j < 4; j++) o[i][j] = 0.f;
        for (int d = 0; d < 64; d++) {
            float qv[4];
#pragma unroll
            for (int i = 0; i < 4; i++) qv[i] = Qf[(4 * tt + i) * 68 + d];
#pragma unroll
            for (int j = 0; j < 4; j++) {
                float sv = Sf[(4 * sx + j) * 68 + d];
#pragma unroll
                for (int i = 0; i < 4; i++) o[i][j] += qv[i] * sv;
            }
        }
        for (int s = 0; s < 64; s++) {
            float mv[4];
#pragma unroll
            for (int i = 0; i < 4; i++) mv[i] = Ms[(4 * tt + i) * 65 + s];
            uint2 yp2 = *(const uint2*)&Yp[s * 34 + 2 * sx];
            float yv0 = b2f_lo(yp2.x), yv1 = b2f_hi(yp2.x), yv2 = b2f_lo(yp2.y), yv3 = b2f_hi(yp2.y);
#pragma unroll
            for (int i = 0; i < 4; i++) {
                o[i][0] += mv[i] * yv0; o[i][1] += mv[i] * yv1;
                o[i][2] += mv[i] * yv2; o[i][3] += mv[i] * yv3;
            }
        }
#pragma unroll
        for (int i = 0; i < 4; i++) {
            uint2 op; op.x = packbf2(o[i][0], o[i][1]); op.y = packbf2(o[i][2], o[i][3]);
            *(uint2*)(attn + (size_t)(b * 2048 + chunk * 64 + 4 * tt + i) * 1024 + h * 64 + 4 * sx) = op;
        }
    }
}

// ---------- workspace layout ----------
static constexpr size_t OFF_H     = 0;                         // 16,777,216  hbuf bf16 / Sall bf16
static constexpr size_t OFF_WQKVT = OFF_H + 16777216;          //  6,553,600
static constexpr size_t OFF_WOT   = OFF_WQKVT + 6553600;       //  2,097,152
static constexpr size_t OFF_W1T   = OFF_WOT + 2097152;         //  8,388,608
static constexpr size_t OFF_W2T   = OFF_W1T + 8388608;         //  8,388,608
static constexpr size_t OFF_BIAS  = OFF_W2T + 8388608;         //     16,384
static constexpr size_t OFF_QKV   = OFF_BIAS + 16384;          // 104,857,600 f32 (later gbuf bf16)
static constexpr size_t OFF_ATTN  = OFF_QKV + 104857600;       // 16,777,216  bf16
static constexpr size_t OFF_Y1    = OFF_ATTN + 16777216;       // 33,554,432  f32 y1 / (W,Z|Y bf16 during scan)

extern "C" void kernel_launch(void* const* d_in, const int* in_sizes, int n_in,
                              void* d_out, int out_size, void* d_ws, size_t ws_size,
                              hipStream_t stream)
{
    const float* x     = (const float*)d_in[0];
    const float* wq    = (const float*)d_in[1];
    const float* bq    = (const float*)d_in[2];
    const float* wk    = (const float*)d_in[3];
    const float* bk    = (const float*)d_in[4];
    const float* wv    = (const float*)d_in[5];
    const float* bv    = (const float*)d_in[6];
    const float* wbeta = (const float*)d_in[7];
    const float* bbeta = (const float*)d_in[8];
    const float* wo    = (const float*)d_in[9];
    const float* bo    = (const float*)d_in[10];
    const float* w1    = (const float*)d_in[11];
    const float* b1    = (const float*)d_in[12];
    const float* w2    = (const float*)d_in[13];
    const float* b2    = (const float*)d_in[14];
    const float* ln1   = (const float*)d_in[15];
    const float* ln2   = (const float*)d_in[16];

    char* ws = (char*)d_ws;
    unsigned short* hbuf  = (unsigned short*)(ws + OFF_H);
    unsigned short* Sall  = (unsigned short*)(ws + OFF_H);
    unsigned short* wqkvT = (unsigned short*)(ws + OFF_WQKVT);
    unsigned short* woT   = (unsigned short*)(ws + OFF_WOT);
    unsigned short* w1T   = (unsigned short*)(ws + OFF_W1T);
    unsigned short* w2T   = (unsigned short*)(ws + OFF_W2T);
    float*          biasc = (float*)(ws + OFF_BIAS);
    float*          qkv   = (float*)(ws + OFF_QKV);
    unsigned short* gbuf  = (unsigned short*)(ws + OFF_QKV);   // reuse after scan
    unsigned short* attn  = (unsigned short*)(ws + OFF_ATTN);
    float*          y1    = (float*)(ws + OFF_Y1);
    unsigned short* Wg    = (unsigned short*)(ws + OFF_Y1);
    unsigned short* Zg    = (unsigned short*)(ws + OFF_Y1 + 16777216);
    float*          out   = (float*)d_out;

    // weight transpose+cast (B^T bf16 operands)
    transpose_cast_k<<<dim3(32, 32), 256, 0, stream>>>(wq, wqkvT,               1024, 1024);
    transpose_cast_k<<<dim3(32, 32), 256, 0, stream>>>(wk, wqkvT + 1024 * 1024, 1024, 1024);
    transpose_cast_k<<<dim3(32, 32), 256, 0, stream>>>(wv, wqkvT + 2048 * 1024, 1024, 1024);
    transpose_cast_k<<<dim3(32, 4),  256, 0, stream>>>(wbeta, wqkvT + 3072 * 1024, 1024, 16);
    transpose_cast_k<<<dim3(32, 32), 256, 0, stream>>>(wo, woT, 1024, 1024);
    transpose_cast_k<<<dim3(32, 128), 256, 0, stream>>>(w1, w1T, 1024, 4096);
    transpose_cast_k<<<dim3(128, 32), 256, 0, stream>>>(w2, w2T, 4096, 1024);
    build_bias_k<<<13, 256, 0, stream>>>(bq, bk, bv, bbeta, biasc);

    // layer
    rmsnorm_cast_k<<<8192, 256, 0, stream>>>(x, ln1, hbuf);
    gemm_bt<0><<<dim3(64, 25), 256, 0, stream>>>(hbuf, wqkvT, biasc, nullptr, qkv, 3200, 1024);
    gdn_prep<<<dim3(32, 64), 256, 0, stream>>>(qkv, Wg, Zg);
    gdn_prop<<<dim3(4, 64), 256, 0, stream>>>(qkv, Wg, Zg, Sall);
    gdn_out<<<dim3(32, 64), 256, 0, stream>>>(qkv, Zg, Sall, attn);
    gemm_bt<1><<<dim3(64, 8), 256, 0, stream>>>(attn, woT, bo, x, y1, 1024, 1024);
    rmsnorm_cast_k<<<8192, 256, 0, stream>>>(y1, ln2, hbuf);
    gemm_bt<2><<<dim3(64, 32), 256, 0, stream>>>(hbuf, w1T, b1, nullptr, gbuf, 4096, 1024);
    gemm_bt<1><<<dim3(64, 8), 256, 0, stream>>>(gbuf, w2T, b2, y1, out, 1024, 4096);
}

// Round 3
// 716.019 us; speedup vs baseline: 2.0440x; 1.1375x over previous
//
#include <hip/hip_runtime.h>

#define DEV __device__ __forceinline__

typedef short bf16x8 __attribute__((ext_vector_type(8)));
typedef float f32x4 __attribute__((ext_vector_type(4)));
typedef unsigned int uint;

// ---------- helpers ----------
DEV unsigned short f2b(float f) {               // fp32 -> bf16 RNE
    uint u = __float_as_uint(f);
    u += 0x7fffu + ((u >> 16) & 1u);
    return (unsigned short)(u >> 16);
}
DEV uint packbf2(float a, float b) { return (uint)f2b(a) | ((uint)f2b(b) << 16); }
DEV float b2f(unsigned short s) { return __uint_as_float(((uint)s) << 16); }
DEV float b2f_lo(uint u) { return __uint_as_float(u << 16); }
DEV float b2f_hi(uint u) { return __uint_as_float(u & 0xffff0000u); }

DEV void async_cp16(const void* g, void* l) {   // global -> LDS, 16B/lane
    __builtin_amdgcn_global_load_lds(
        (const __attribute__((address_space(1))) unsigned int*)g,
        (__attribute__((address_space(3))) unsigned int*)l, 16, 0, 0);
}

DEV float quad_sum(float x) {                   // sum over 4-lane quad via DPP
    x += __int_as_float(__builtin_amdgcn_update_dpp(0, __float_as_int(x), 0xB1, 0xF, 0xF, true));
    x += __int_as_float(__builtin_amdgcn_update_dpp(0, __float_as_int(x), 0x4E, 0xF, 0xF, true));
    return x;
}

// decode 8 bf16 (uint4) -> 8 floats
DEV void dec8(uint4 p, float* o) {
    o[0] = b2f_lo(p.x); o[1] = b2f_hi(p.x); o[2] = b2f_lo(p.y); o[3] = b2f_hi(p.y);
    o[4] = b2f_lo(p.z); o[5] = b2f_hi(p.z); o[6] = b2f_lo(p.w); o[7] = b2f_hi(p.w);
}

// ---------- transpose + cast: in f32 [K][N] -> out bf16 [Npad][K], rows >= N zero ----------
__global__ __launch_bounds__(256) void transpose_cast_k(
    const float* __restrict__ in, unsigned short* __restrict__ out, int K, int N)
{
    __shared__ float tile[32][33];
    const int k0 = blockIdx.x * 32, n0 = blockIdx.y * 32;
    const int tx = threadIdx.x & 31, ty = threadIdx.x >> 5;   // ty 0..7
#pragma unroll
    for (int i = 0; i < 32; i += 8) {
        int n = n0 + tx;
        tile[ty + i][tx] = (n < N) ? in[(size_t)(k0 + ty + i) * N + n] : 0.0f;
    }
    __syncthreads();
#pragma unroll
    for (int i = 0; i < 32; i += 8) {
        out[(size_t)(n0 + ty + i) * K + (k0 + tx)] = f2b(tile[tx][ty + i]);
    }
}

// ---------- concat bias [bq|bk|bv|bbeta|0pad] -> 3200 ----------
__global__ void build_bias_k(const float* __restrict__ bq, const float* __restrict__ bk,
                             const float* __restrict__ bv, const float* __restrict__ bb,
                             float* __restrict__ outb)
{
    int i = blockIdx.x * 256 + threadIdx.x;
    if (i >= 3200) return;
    float v = 0.f;
    if (i < 1024)      v = bq[i];
    else if (i < 2048) v = bk[i - 1024];
    else if (i < 3072) v = bv[i - 2048];
    else if (i < 3088) v = bb[i - 3072];
    outb[i] = v;
}

// ---------- rmsnorm (rows of 1024) + cast to bf16 ----------
__global__ __launch_bounds__(256) void rmsnorm_cast_k(
    const float* __restrict__ x, const float* __restrict__ scale,
    unsigned short* __restrict__ out)
{
    const int row = blockIdx.x;
    const int t = threadIdx.x;
    const float4 v = *(const float4*)(x + (size_t)row * 1024 + t * 4);
    float ss = v.x * v.x + v.y * v.y + v.z * v.z + v.w * v.w;
#pragma unroll
    for (int off = 1; off < 64; off <<= 1) ss += __shfl_xor(ss, off);
    __shared__ float wsum[4];
    if ((t & 63) == 0) wsum[t >> 6] = ss;
    __syncthreads();
    const float tot = wsum[0] + wsum[1] + wsum[2] + wsum[3];
    const float inv = rsqrtf(tot * (1.0f / 1024.0f) + 1e-6f);
    const float4 sc = *(const float4*)(scale + t * 4);
    uint lo = (uint)f2b(v.x * inv * sc.x) | ((uint)f2b(v.y * inv * sc.y) << 16);
    uint hi = (uint)f2b(v.z * inv * sc.z) | ((uint)f2b(v.w * inv * sc.w) << 16);
    uint2 pkd; pkd.x = lo; pkd.y = hi;
    *(uint2*)(out + (size_t)row * 1024 + t * 4) = pkd;
}

// ---------- GEMM: C[M,N] = A[M,K](bf16) * BT[N,K](bf16)^T, m97 structure ----------
// MODE 0: C=f32 +bias   MODE 1: C=f32 +bias+add   MODE 2: C=bf16 gelu(+bias)   MODE 3: C=bf16 +bias
template <int MODE>
__global__ __launch_bounds__(256) void gemm_bt(
    const unsigned short* __restrict__ A, const unsigned short* __restrict__ BT,
    const float* __restrict__ bias, const float* __restrict__ add,
    void* __restrict__ Cout, int N, int K)
{
    __shared__ unsigned short As[128 * 32];
    __shared__ unsigned short Bs[128 * 32];
    const int tid = threadIdx.x;
    const int wid = tid >> 6;
    const int lane = tid & 63;
    const int m0 = blockIdx.x * 128;
    const int n0 = blockIdx.y * 128;

    const int lrow = lane >> 2;         // 0..15
    const int lkw = (lane & 3) * 8;     // ushort offset within 32-wide k row

    const unsigned short* Ag0 = A + (size_t)(m0 + wid * 16 + lrow) * K + lkw;
    const unsigned short* Ag1 = A + (size_t)(m0 + wid * 16 + 64 + lrow) * K + lkw;
    const unsigned short* Bg0 = BT + (size_t)(n0 + wid * 16 + lrow) * K + lkw;
    const unsigned short* Bg1 = BT + (size_t)(n0 + wid * 16 + 64 + lrow) * K + lkw;
    unsigned short* As0 = &As[(wid * 16) * 32];
    unsigned short* As1 = &As[(wid * 16 + 64) * 32];
    unsigned short* Bs0 = &Bs[(wid * 16) * 32];
    unsigned short* Bs1 = &Bs[(wid * 16 + 64) * 32];

    f32x4 acc[4][4];
#pragma unroll
    for (int i = 0; i < 4; i++)
#pragma unroll
        for (int j = 0; j < 4; j++) acc[i][j] = (f32x4)0.f;

    const int wm = (wid & 1) * 64;
    const int wn = (wid >> 1) * 64;
    const int l16 = lane & 15;
    const int koff = (lane >> 4) * 8;

    for (int k0 = 0; k0 < K; k0 += 32) {
        async_cp16(Ag0 + k0, As0);
        async_cp16(Ag1 + k0, As1);
        async_cp16(Bg0 + k0, Bs0);
        async_cp16(Bg1 + k0, Bs1);
        __syncthreads();
        bf16x8 af[4], bfv[4];
#pragma unroll
        for (int i = 0; i < 4; i++) af[i] = *(const bf16x8*)&As[(wm + i * 16 + l16) * 32 + koff];
#pragma unroll
        for (int j = 0; j < 4; j++) bfv[j] = *(const bf16x8*)&Bs[(wn + j * 16 + l16) * 32 + koff];
#pragma unroll
        for (int i = 0; i < 4; i++)
#pragma unroll
            for (int j = 0; j < 4; j++)
                acc[i][j] = __builtin_amdgcn_mfma_f32_16x16x32_bf16(af[i], bfv[j], acc[i][j], 0, 0, 0);
        __syncthreads();
    }

#pragma unroll
    for (int j = 0; j < 4; j++) {
        const int cg = n0 + wn + j * 16 + l16;
        const float bv = bias[cg];
#pragma unroll
        for (int i = 0; i < 4; i++) {
            const int rg0 = m0 + wm + i * 16 + (lane >> 4) * 4;
#pragma unroll
            for (int r = 0; r < 4; r++) {
                size_t idx = (size_t)(rg0 + r) * N + cg;
                float v = acc[i][j][r] + bv;
                if (MODE == 1) v += add[idx];
                if (MODE == 2) {
                    float u = v;
                    float t = tanhf(0.7978845608028654f * (u + 0.044715f * u * u * u));
                    ((unsigned short*)Cout)[idx] = f2b(0.5f * u * (1.f + t));
                } else if (MODE == 3) {
                    ((unsigned short*)Cout)[idx] = f2b(v);
                } else {
                    ((float*)Cout)[idx] = v;
                }
            }
        }
    }
}

// =====================================================================
// Chunked WY delta-rule scan, chunk L=64 (all bf16 tensors, MFMA prop).
// Tiled global layouts per (bh,ch), flat 4096 ush = 8KB:
//   Wg  : [g_d(8)][t(64)][8]   W[t][d]
//   KTg : [g_t(8)][d(64)][8]   Kn[t][d] transposed
//   ZTg : [g_t(8)][j(64)][8]   Z[t][j] transposed
//   Sall: [d(64)][j(64)]       chunk-start S (S[j][d] stored d-major)
//   Yg  : [t(64)][j(64)]       Y row-major
// =====================================================================

// ---------- prep: normalize k in place (bf16 qkv), build A, solve W,Z, emit tiled layouts ----------
__global__ __launch_bounds__(256) void gdn_prep(
    unsigned short* __restrict__ qkv, unsigned short* __restrict__ Wg,
    unsigned short* __restrict__ ZTg, unsigned short* __restrict__ KTg)
{
    const int chunk = blockIdx.x, bh = blockIdx.y;
    const int b = bh >> 4, h = bh & 15;
    __shared__ float Ks[64 * 68];
    __shared__ float Ws[64 * 65];
    __shared__ float Zs[64 * 65];
    __shared__ float Asl[64 * 65];
    __shared__ float bs[64];
    const int tid = threadIdx.x;
    const int t = tid >> 2, c = tid & 3;
    unsigned short* rowp = qkv + (size_t)(b * 2048 + chunk * 64 + t) * 3200;

    // phase 1a: load k slice (bf16), row norm, write Kn to LDS + back to global
    float kn[16];
    {
        uint4 ka = *(const uint4*)(rowp + 1024 + h * 64 + 16 * c);
        uint4 kb = *(const uint4*)(rowp + 1024 + h * 64 + 16 * c + 8);
        dec8(ka, kn); dec8(kb, kn + 8);
    }
    float ss = 0.f;
#pragma unroll
    for (int j = 0; j < 16; j++) ss += kn[j] * kn[j];
    ss = quad_sum(ss);
    const float inv = 1.f / (sqrtf(ss) + 1e-6f);
#pragma unroll
    for (int j = 0; j < 16; j++) kn[j] *= inv;
#pragma unroll
    for (int j = 0; j < 16; j++) Ks[t * 68 + 16 * c + j] = kn[j];
    {
        uint4 p0, p1;
        p0.x = packbf2(kn[0], kn[1]);  p0.y = packbf2(kn[2], kn[3]);
        p0.z = packbf2(kn[4], kn[5]);  p0.w = packbf2(kn[6], kn[7]);
        p1.x = packbf2(kn[8], kn[9]);  p1.y = packbf2(kn[10], kn[11]);
        p1.z = packbf2(kn[12], kn[13]); p1.w = packbf2(kn[14], kn[15]);
        *(uint4*)(rowp + 1024 + h * 64 + 16 * c) = p0;
        *(uint4*)(rowp + 1024 + h * 64 + 16 * c + 8) = p1;
    }
    if (c == 0) bs[t] = 1.f / (1.f + __expf(-b2f(rowp[3072 + h])));
    __syncthreads();

    // phase 1b: RHS: W = beta*Kn, Z = beta*V
    const float beta = bs[t];
#pragma unroll
    for (int j = 0; j < 16; j++) Ws[t * 65 + 16 * c + j] = beta * kn[j];
    {
        float vv[16];
        uint4 va = *(const uint4*)(rowp + 2048 + h * 64 + 16 * c);
        uint4 vb = *(const uint4*)(rowp + 2048 + h * 64 + 16 * c + 8);
        dec8(va, vv); dec8(vb, vv + 8);
#pragma unroll
        for (int j = 0; j < 16; j++) Zs[t * 65 + 16 * c + j] = beta * vv[j];
    }
    __syncthreads();

    // phase 2: A = strictly_lower(diag(beta) Kn Kn^T); 4x4 tile per thread
    {
        const int tt = tid >> 4, sx = tid & 15;
        float dm[4][4];
#pragma unroll
        for (int i = 0; i < 4; i++)
#pragma unroll
            for (int j = 0; j < 4; j++) dm[i][j] = 0.f;
        for (int d = 0; d < 64; d++) {
            float kt[4], ksv[4];
#pragma unroll
            for (int i = 0; i < 4; i++) kt[i] = Ks[(4 * tt + i) * 68 + d];
#pragma unroll
            for (int j = 0; j < 4; j++) ksv[j] = Ks[(4 * sx + j) * 68 + d];
#pragma unroll
            for (int i = 0; i < 4; i++)
#pragma unroll
                for (int j = 0; j < 4; j++) dm[i][j] += kt[i] * ksv[j];
        }
#pragma unroll
        for (int i = 0; i < 4; i++)
#pragma unroll
            for (int j = 0; j < 4; j++) {
                int T = 4 * tt + i, S_ = 4 * sx + j;
                Asl[T * 65 + S_] = (S_ < T) ? bs[T] * dm[i][j] : 0.f;
            }
    }
    __syncthreads();

    // phase 3: blocked forward substitution (I+A)X = RHS for W and Z
    {
        const int wid = tid >> 6, lane = tid & 63;  // lane = d
        for (int qi = 0; qi < 4; qi++) {
            if (qi > 0) {
                const int tb = qi * 16 + wid * 4;
                float aw[4], az[4];
#pragma unroll
                for (int i = 0; i < 4; i++) { aw[i] = Ws[(tb + i) * 65 + lane]; az[i] = Zs[(tb + i) * 65 + lane]; }
                for (int s = 0; s < qi * 16; s++) {
                    float wsv = Ws[s * 65 + lane], zsv = Zs[s * 65 + lane];
#pragma unroll
                    for (int i = 0; i < 4; i++) {
                        float a = Asl[(tb + i) * 65 + s];
                        aw[i] -= a * wsv; az[i] -= a * zsv;
                    }
                }
#pragma unroll
                for (int i = 0; i < 4; i++) { Ws[(tb + i) * 65 + lane] = aw[i]; Zs[(tb + i) * 65 + lane] = az[i]; }
            }
            __syncthreads();
            if (wid == 0) {
                for (int T = qi * 16; T < qi * 16 + 16; T++) {
                    float a_ = Ws[T * 65 + lane];
                    for (int s = qi * 16; s < T; s++) a_ -= Asl[T * 65 + s] * Ws[s * 65 + lane];
                    Ws[T * 65 + lane] = a_;
                }
            } else if (wid == 1) {
                for (int T = qi * 16; T < qi * 16 + 16; T++) {
                    float a_ = Zs[T * 65 + lane];
                    for (int s = qi * 16; s < T; s++) a_ -= Asl[T * 65 + s] * Zs[s * 65 + lane];
                    Zs[T * 65 + lane] = a_;
                }
            }
            __syncthreads();
        }
    }

    // phase 4: tiled bf16 outputs
    const size_t cbase = ((size_t)bh * 32 + chunk) * 4096;
    // Wg [g_d][t][8] from Ws[t][d]
    {
#pragma unroll
        for (int half = 0; half < 2; half++) {
            uint4 w4;
            w4.x = packbf2(Ws[t * 65 + 16 * c + half * 8 + 0], Ws[t * 65 + 16 * c + half * 8 + 1]);
            w4.y = packbf2(Ws[t * 65 + 16 * c + half * 8 + 2], Ws[t * 65 + 16 * c + half * 8 + 3]);
            w4.z = packbf2(Ws[t * 65 + 16 * c + half * 8 + 4], Ws[t * 65 + 16 * c + half * 8 + 5]);
            w4.w = packbf2(Ws[t * 65 + 16 * c + half * 8 + 6], Ws[t * 65 + 16 * c + half * 8 + 7]);
            *(uint4*)(Wg + cbase + (size_t)((2 * c + half) * 64 + t) * 8) = w4;
        }
    }
    // ZTg [g_t][j][8] from Zs[t][j]  (thread: jj = tid>>2, tq = tid&3)
    {
        const int jj = tid >> 2, tq = tid & 3;
#pragma unroll
        for (int half = 0; half < 2; half++) {
            uint4 z4;
            int i0 = half * 8;
            z4.x = packbf2(Zs[(16 * tq + i0 + 0) * 65 + jj], Zs[(16 * tq + i0 + 1) * 65 + jj]);
            z4.y = packbf2(Zs[(16 * tq + i0 + 2) * 65 + jj], Zs[(16 * tq + i0 + 3) * 65 + jj]);
            z4.z = packbf2(Zs[(16 * tq + i0 + 4) * 65 + jj], Zs[(16 * tq + i0 + 5) * 65 + jj]);
            z4.w = packbf2(Zs[(16 * tq + i0 + 6) * 65 + jj], Zs[(16 * tq + i0 + 7) * 65 + jj]);
            *(uint4*)(ZTg + cbase + (size_t)((2 * tq + half) * 64 + jj) * 8) = z4;
        }
    }
    // KTg [g_t][d][8] from Ks[t][d]
    {
        const int dd = tid >> 2, tq = tid & 3;
#pragma unroll
        for (int half = 0; half < 2; half++) {
            uint4 k4;
            int i0 = half * 8;
            k4.x = packbf2(Ks[(16 * tq + i0 + 0) * 68 + dd], Ks[(16 * tq + i0 + 1) * 68 + dd]);
            k4.y = packbf2(Ks[(16 * tq + i0 + 2) * 68 + dd], Ks[(16 * tq + i0 + 3) * 68 + dd]);
            k4.z = packbf2(Ks[(16 * tq + i0 + 4) * 68 + dd], Ks[(16 * tq + i0 + 5) * 68 + dd]);
            k4.w = packbf2(Ks[(16 * tq + i0 + 6) * 68 + dd], Ks[(16 * tq + i0 + 7) * 68 + dd]);
            *(uint4*)(KTg + cbase + (size_t)((2 * tq + half) * 64 + dd) * 8) = k4;
        }
    }
}

// ---------- prop (MFMA): 64 blocks (bh), 4 waves; wave w owns j-rows 16w..16w+15 ----------
// per chunk: T1^T = S*W^T (MFMA), Y = Z - T1, S += Y^T*Kn (MFMA). S lives in f32 C-frags.
__global__ __launch_bounds__(256, 1) void gdn_prop_mfma(
    const unsigned short* __restrict__ Wg, const unsigned short* __restrict__ KTg,
    const unsigned short* __restrict__ ZTg, unsigned short* __restrict__ Sall,
    unsigned short* __restrict__ Yg)
{
    const int bh = blockIdx.x;
    __shared__ unsigned short WbU[4096];   // [g_d][t][8]
    __shared__ unsigned short KTbU[4096];  // [g_t][d][8]
    __shared__ unsigned short ZTbU[4096];  // [g_t][j][8]; overwritten by Y in place
    __shared__ unsigned short SbU[4096];   // [g_d][j][8]
    const int tid = threadIdx.x;
    const int wid = tid >> 6;
    const int lane = tid & 63;
    const int l16 = lane & 15, quad = lane >> 4;

    f32x4 Sacc[4];   // C-frag tiles (M = j-block wid, N = d-tile dt): (j=16wid+quad*4+r, d=16dt+l16)
#pragma unroll
    for (int dt = 0; dt < 4; dt++) Sacc[dt] = (f32x4)0.f;

    for (int ch = 0; ch < 32; ch++) {
        const size_t cbase = ((size_t)bh * 32 + ch) * 4096;
        // stage (flat tiled copies; 2 chunks of 1KB per wave per buffer)
#pragma unroll
        for (int p = 0; p < 2; p++) {
            const int n = wid * 2 + p;
            async_cp16(Wg + cbase + n * 512 + lane * 8, &WbU[n * 512]);
            async_cp16(KTg + cbase + n * 512 + lane * 8, &KTbU[n * 512]);
            async_cp16(ZTg + cbase + n * 512 + lane * 8, &ZTbU[n * 512]);
        }
        // pack S -> Sb bf16 [g_d][j][8]; snapshot chunk-start S -> Sall [d][j] direct from regs
#pragma unroll
        for (int dt = 0; dt < 4; dt++) {
#pragma unroll
            for (int r = 0; r < 4; r++) {
                const int j = wid * 16 + quad * 4 + r;
                SbU[((2 * dt + (l16 >> 3)) * 64 + j) * 8 + (l16 & 7)] = f2b(Sacc[dt][r]);
            }
            const int d = dt * 16 + l16;
            uint2 sp;
            sp.x = packbf2(Sacc[dt][0], Sacc[dt][1]);
            sp.y = packbf2(Sacc[dt][2], Sacc[dt][3]);
            *(uint2*)(Sall + cbase + d * 64 + wid * 16 + quad * 4) = sp;
        }
        __syncthreads();   // drains global_load_lds (vmcnt 0) + Sb visible

        // MFMA1': T1^T[j][t] = sum_d Sb[j][d] * Wb[t][d]
        f32x4 t1[4];
#pragma unroll
        for (int tt = 0; tt < 4; tt++) t1[tt] = (f32x4)0.f;
#pragma unroll
        for (int kh = 0; kh < 2; kh++) {
            const int g = kh * 4 + quad;
            bf16x8 afr = *(const bf16x8*)&SbU[(g * 64 + wid * 16 + l16) * 8];
#pragma unroll
            for (int tt = 0; tt < 4; tt++) {
                bf16x8 bfr = *(const bf16x8*)&WbU[(g * 64 + tt * 16 + l16) * 8];
                t1[tt] = __builtin_amdgcn_mfma_f32_16x16x32_bf16(afr, bfr, t1[tt], 0, 0, 0);
            }
        }
        // Y = Z - T1: in-place into ZTb (as YT[j][t]) + direct packed store to Yg[t][j]
#pragma unroll
        for (int tt = 0; tt < 4; tt++) {
            const int t = tt * 16 + l16;
            const int gb = (t >> 3) * 64;
            unsigned short ybf[4];
#pragma unroll
            for (int r = 0; r < 4; r++) {
                const int j = wid * 16 + quad * 4 + r;
                const float z = b2f(ZTbU[(gb + j) * 8 + (t & 7)]);
                ybf[r] = f2b(z - t1[tt][r]);
            }
#pragma unroll
            for (int r = 0; r < 4; r++) {
                const int j = wid * 16 + quad * 4 + r;
                ZTbU[(gb + j) * 8 + (t & 7)] = ybf[r];
            }
            uint2 yp;
            yp.x = (uint)ybf[0] | ((uint)ybf[1] << 16);
            yp.y = (uint)ybf[2] | ((uint)ybf[3] << 16);
            *(uint2*)(Yg + cbase + t * 64 + wid * 16 + quad * 4) = yp;
        }
        // MFMA2: S[j][d] += sum_t YT[j][t] * KT[d][t]   (wave reads only its own j rows of Y)
#pragma unroll
        for (int kh = 0; kh < 2; kh++) {
            const int g = kh * 4 + quad;
            bf16x8 afr = *(const bf16x8*)&ZTbU[(g * 64 + wid * 16 + l16) * 8];
#pragma unroll
            for (int dt = 0; dt < 4; dt++) {
                bf16x8 bfr = *(const bf16x8*)&KTbU[(g * 64 + dt * 16 + l16) * 8];
                Sacc[dt] = __builtin_amdgcn_mfma_f32_16x16x32_bf16(afr, bfr, Sacc[dt], 0, 0, 0);
            }
        }
        __syncthreads();   // all waves done with Wb/KTb/ZTb before restage
    }
}

// ---------- output: per (bh, chunk): O = Q S_c^T + tril(Q Kn^T) Y ----------
__global__ __launch_bounds__(256) void gdn_out(
    const unsigned short* __restrict__ qkv, const unsigned short* __restrict__ Yg,
    const unsigned short* __restrict__ Sall, unsigned short* __restrict__ attn)
{
    const int chunk = blockIdx.x, bh = blockIdx.y;
    const int b = bh >> 4, h = bh & 15;
    __shared__ float Qf[64 * 68];
    __shared__ float SfT[64 * 68];   // [d][j]
    __shared__ float Ms[64 * 65];
    __shared__ uint Kp[64 * 33];
    __shared__ uint Yp[64 * 34];
    const int tid = threadIdx.x;
    const int t = tid >> 2, c = tid & 3;
    const size_t cbase = ((size_t)bh * 32 + chunk) * 4096;

    // stage
    {
        const unsigned short* rowp = qkv + (size_t)(b * 2048 + chunk * 64 + t) * 3200;
        float qv[16];
        uint4 qa = *(const uint4*)(rowp + h * 64 + 16 * c);
        uint4 qb = *(const uint4*)(rowp + h * 64 + 16 * c + 8);
        dec8(qa, qv); dec8(qb, qv + 8);
#pragma unroll
        for (int m = 0; m < 16; m++) Qf[t * 68 + 16 * c + m] = qv[m];
        // Kn already bf16-packed pairs in qkv
        uint4 ka = *(const uint4*)(rowp + 1024 + h * 64 + 16 * c);
        uint4 kb = *(const uint4*)(rowp + 1024 + h * 64 + 16 * c + 8);
        Kp[t * 33 + 8 * c + 0] = ka.x; Kp[t * 33 + 8 * c + 1] = ka.y;
        Kp[t * 33 + 8 * c + 2] = ka.z; Kp[t * 33 + 8 * c + 3] = ka.w;
        Kp[t * 33 + 8 * c + 4] = kb.x; Kp[t * 33 + 8 * c + 5] = kb.y;
        Kp[t * 33 + 8 * c + 6] = kb.z; Kp[t * 33 + 8 * c + 7] = kb.w;
        // Y rows [t][j]
        const unsigned short* yrow = Yg + cbase + t * 64 + 16 * c;
        uint4 ya = *(const uint4*)yrow;
        uint4 yb = *(const uint4*)(yrow + 8);
        Yp[t * 34 + 8 * c + 0] = ya.x; Yp[t * 34 + 8 * c + 1] = ya.y;
        Yp[t * 34 + 8 * c + 2] = ya.z; Yp[t * 34 + 8 * c + 3] = ya.w;
        Yp[t * 34 + 8 * c + 4] = yb.x; Yp[t * 34 + 8 * c + 5] = yb.y;
        Yp[t * 34 + 8 * c + 6] = yb.z; Yp[t * 34 + 8 * c + 7] = yb.w;
        // S_c rows [d][j] -> SfT f32 (here t indexes d)
        const unsigned short* srow = Sall + cbase + t * 64 + 16 * c;
        float sv[16];
        uint4 sa = *(const uint4*)srow;
        uint4 sb = *(const uint4*)(srow + 8);
        dec8(sa, sv); dec8(sb, sv + 8);
#pragma unroll
        for (int m = 0; m < 16; m++) SfT[t * 68 + 16 * c + m] = sv[m];
    }
    __syncthreads();

    const int tt = tid >> 4, sx = tid & 15;
    // M = tril(Q Kn^T) incl diag
    {
        float dm[4][4];
#pragma unroll
        for (int i = 0; i < 4; i++)
#pragma unroll
            for (int j = 0; j < 4; j++) dm[i][j] = 0.f;
        for (int p = 0; p < 32; p++) {
            float q0[4], q1[4];
#pragma unroll
            for (int i = 0; i < 4; i++) {
                q0[i] = Qf[(4 * tt + i) * 68 + 2 * p];
                q1[i] = Qf[(4 * tt + i) * 68 + 2 * p + 1];
            }
#pragma unroll
            for (int j = 0; j < 4; j++) {
                uint kp = Kp[(4 * sx + j) * 33 + p];
                float kk0 = b2f_lo(kp), kk1 = b2f_hi(kp);
#pragma unroll
                for (int i = 0; i < 4; i++) dm[i][j] += q0[i] * kk0 + q1[i] * kk1;
            }
        }
#pragma unroll
        for (int i = 0; i < 4; i++)
#pragma unroll
            for (int j = 0; j < 4; j++) {
                int T = 4 * tt + i, S_ = 4 * sx + j;
                Ms[T * 65 + S_] = (S_ <= T) ? dm[i][j] : 0.f;
            }
    }
    __syncthreads();

    // O[4tt..][4sx..]: part1 Q S_c^T + part2 M Y
    {
        float o[4][4];
#pragma unroll
        for (int i = 0; i < 4; i++)
#pragma unroll
            for (int j = 0; j < 4; j++) o[i][j] = 0.f;
        for (int d = 0; d < 64; d++) {
            float qv[4];
#pragma unroll
            for (int i = 0; i < 4; i++) qv[i] = Qf[(4 * tt + i) * 68 + d];
#pragma unroll
            for (int j = 0; j < 4; j++) {
                float sv = SfT[d * 68 + 4 * sx + j];
#pragma unroll
                for (int i = 0; i < 4; i++) o[i][j] += qv[i] * sv;
            }
        }
        for (int s = 0; s < 64; s++) {
            float mv[4];
#pragma unroll
            for (int i = 0; i < 4; i++) mv[i] = Ms[(4 * tt + i) * 65 + s];
            uint2 yp2 = *(const uint2*)&Yp[s * 34 + 2 * sx];
            float yv0 = b2f_lo(yp2.x), yv1 = b2f_hi(yp2.x), yv2 = b2f_lo(yp2.y), yv3 = b2f_hi(yp2.y);
#pragma unroll
            for (int i = 0; i < 4; i++) {
                o[i][0] += mv[i] * yv0; o[i][1] += mv[i] * yv1;
                o[i][2] += mv[i] * yv2; o[i][3] += mv[i] * yv3;
            }
        }
#pragma unroll
        for (int i = 0; i < 4; i++) {
            uint2 op; op.x = packbf2(o[i][0], o[i][1]); op.y = packbf2(o[i][2], o[i][3]);
            *(uint2*)(attn + (size_t)(b * 2048 + chunk * 64 + 4 * tt + i) * 1024 + h * 64 + 4 * sx) = op;
        }
    }
}

// ---------- workspace layout (bytes) ----------
static constexpr size_t OFF_H     = 0;                          // 16,777,216  hbuf bf16 / Sall bf16
static constexpr size_t OFF_WQKVT = OFF_H + 16777216;           //  6,553,600
static constexpr size_t OFF_WOT   = OFF_WQKVT + 6553600;        //  2,097,152
static constexpr size_t OFF_W1T   = OFF_WOT + 2097152;          //  8,388,608
static constexpr size_t OFF_W2T   = OFF_W1T + 8388608;          //  8,388,608
static constexpr size_t OFF_BIAS  = OFF_W2T + 8388608;          //     16,384
static constexpr size_t OFF_QKV   = OFF_BIAS + 16384;           // 67,108,864  qkv bf16 (52.4MB) / gbuf bf16 (67MB)
static constexpr size_t OFF_ATTN  = OFF_QKV + 67108864;         // 16,777,216  bf16
static constexpr size_t OFF_Y1    = OFF_ATTN + 16777216;        // 33,554,432  y1 f32 / (ZTg+KTg bf16 during scan)
static constexpr size_t OFF_WG    = OFF_Y1 + 33554432;          // 16,777,216  Wg bf16
static constexpr size_t OFF_YG    = OFF_WG + 16777216;          // 16,777,216  Yg bf16

extern "C" void kernel_launch(void* const* d_in, const int* in_sizes, int n_in,
                              void* d_out, int out_size, void* d_ws, size_t ws_size,
                              hipStream_t stream)
{
    const float* x     = (const float*)d_in[0];
    const float* wq    = (const float*)d_in[1];
    const float* bq    = (const float*)d_in[2];
    const float* wk    = (const float*)d_in[3];
    const float* bk    = (const float*)d_in[4];
    const float* wv    = (const float*)d_in[5];
    const float* bv    = (const float*)d_in[6];
    const float* wbeta = (const float*)d_in[7];
    const float* bbeta = (const float*)d_in[8];
    const float* wo    = (const float*)d_in[9];
    const float* bo    = (const float*)d_in[10];
    const float* w1    = (const float*)d_in[11];
    const float* b1    = (const float*)d_in[12];
    const float* w2    = (const float*)d_in[13];
    const float* b2    = (const float*)d_in[14];
    const float* ln1   = (const float*)d_in[15];
    const float* ln2   = (const float*)d_in[16];

    char* ws = (char*)d_ws;
    unsigned short* hbuf  = (unsigned short*)(ws + OFF_H);
    unsigned short* Sall  = (unsigned short*)(ws + OFF_H);
    unsigned short* wqkvT = (unsigned short*)(ws + OFF_WQKVT);
    unsigned short* woT   = (unsigned short*)(ws + OFF_WOT);
    unsigned short* w1T   = (unsigned short*)(ws + OFF_W1T);
    unsigned short* w2T   = (unsigned short*)(ws + OFF_W2T);
    float*          biasc = (float*)(ws + OFF_BIAS);
    unsigned short* qkvU  = (unsigned short*)(ws + OFF_QKV);
    unsigned short* gbuf  = (unsigned short*)(ws + OFF_QKV);   // reuse after scan
    unsigned short* attn  = (unsigned short*)(ws + OFF_ATTN);
    float*          y1    = (float*)(ws + OFF_Y1);
    unsigned short* ZTg   = (unsigned short*)(ws + OFF_Y1);
    unsigned short* KTg   = (unsigned short*)(ws + OFF_Y1 + 16777216);
    unsigned short* Wg    = (unsigned short*)(ws + OFF_WG);
    unsigned short* Yg    = (unsigned short*)(ws + OFF_YG);
    float*          out   = (float*)d_out;

    // weight transpose+cast (B^T bf16 operands)
    transpose_cast_k<<<dim3(32, 32), 256, 0, stream>>>(wq, wqkvT,               1024, 1024);
    transpose_cast_k<<<dim3(32, 32), 256, 0, stream>>>(wk, wqkvT + 1024 * 1024, 1024, 1024);
    transpose_cast_k<<<dim3(32, 32), 256, 0, stream>>>(wv, wqkvT + 2048 * 1024, 1024, 1024);
    transpose_cast_k<<<dim3(32, 4),  256, 0, stream>>>(wbeta, wqkvT + 3072 * 1024, 1024, 16);
    transpose_cast_k<<<dim3(32, 32), 256, 0, stream>>>(wo, woT, 1024, 1024);
    transpose_cast_k<<<dim3(32, 128), 256, 0, stream>>>(w1, w1T, 1024, 4096);
    transpose_cast_k<<<dim3(128, 32), 256, 0, stream>>>(w2, w2T, 4096, 1024);
    build_bias_k<<<13, 256, 0, stream>>>(bq, bk, bv, bbeta, biasc);

    // layer
    rmsnorm_cast_k<<<8192, 256, 0, stream>>>(x, ln1, hbuf);
    gemm_bt<3><<<dim3(64, 25), 256, 0, stream>>>(hbuf, wqkvT, biasc, nullptr, qkvU, 3200, 1024);
    gdn_prep<<<dim3(32, 64), 256, 0, stream>>>(qkvU, Wg, ZTg, KTg);
    gdn_prop_mfma<<<64, 256, 0, stream>>>(Wg, KTg, ZTg, Sall, Yg);
    gdn_out<<<dim3(32, 64), 256, 0, stream>>>(qkvU, Yg, Sall, attn);
    gemm_bt<1><<<dim3(64, 8), 256, 0, stream>>>(attn, woT, bo, x, y1, 1024, 1024);
    rmsnorm_cast_k<<<8192, 256, 0, stream>>>(y1, ln2, hbuf);
    gemm_bt<2><<<dim3(64, 32), 256, 0, stream>>>(hbuf, w1T, b1, nullptr, gbuf, 4096, 1024);
    gemm_bt<1><<<dim3(64, 8), 256, 0, stream>>>(gbuf, w2T, b2, y1, out, 1024, 4096);
}

// Round 4
// 684.244 us; speedup vs baseline: 2.1389x; 1.0464x over previous
//
#include <hip/hip_runtime.h>

#define DEV __device__ __forceinline__

typedef short bf16x8 __attribute__((ext_vector_type(8)));
typedef float f32x4 __attribute__((ext_vector_type(4)));
typedef unsigned int uint;

// ---------- helpers ----------
DEV unsigned short f2b(float f) {               // fp32 -> bf16 RNE
    uint u = __float_as_uint(f);
    u += 0x7fffu + ((u >> 16) & 1u);
    return (unsigned short)(u >> 16);
}
DEV uint packbf2(float a, float b) { return (uint)f2b(a) | ((uint)f2b(b) << 16); }
DEV float b2f(unsigned short s) { return __uint_as_float(((uint)s) << 16); }
DEV float b2f_lo(uint u) { return __uint_as_float(u << 16); }
DEV float b2f_hi(uint u) { return __uint_as_float(u & 0xffff0000u); }

DEV void async_cp16(const void* g, void* l) {   // global -> LDS, 16B/lane
    __builtin_amdgcn_global_load_lds(
        (const __attribute__((address_space(1))) unsigned int*)g,
        (__attribute__((address_space(3))) unsigned int*)l, 16, 0, 0);
}

DEV float quad_sum(float x) {                   // sum over 4-lane quad via DPP
    x += __int_as_float(__builtin_amdgcn_update_dpp(0, __float_as_int(x), 0xB1, 0xF, 0xF, true));
    x += __int_as_float(__builtin_amdgcn_update_dpp(0, __float_as_int(x), 0x4E, 0xF, 0xF, true));
    return x;
}

DEV float gelu_f(float u) {                     // tanh-approx gelu via sigmoid/exp
    float p = u + 0.044715f * u * u * u;
    float e = __expf(-1.5957691216f * p);       // 0.5(1+tanh(cp)) = sigmoid(2cp)
    return __fdividef(u, 1.f + e);
}

// decode 8 bf16 (uint4) -> 8 floats
DEV void dec8(uint4 p, float* o) {
    o[0] = b2f_lo(p.x); o[1] = b2f_hi(p.x); o[2] = b2f_lo(p.y); o[3] = b2f_hi(p.y);
    o[4] = b2f_lo(p.z); o[5] = b2f_hi(p.z); o[6] = b2f_lo(p.w); o[7] = b2f_hi(p.w);
}

// ---------- transpose + cast: in f32 [K][N] -> out bf16 [Npad][K], rows >= N zero ----------
__global__ __launch_bounds__(256) void transpose_cast_k(
    const float* __restrict__ in, unsigned short* __restrict__ out, int K, int N)
{
    __shared__ float tile[32][33];
    const int k0 = blockIdx.x * 32, n0 = blockIdx.y * 32;
    const int tx = threadIdx.x & 31, ty = threadIdx.x >> 5;   // ty 0..7
#pragma unroll
    for (int i = 0; i < 32; i += 8) {
        int n = n0 + tx;
        tile[ty + i][tx] = (n < N) ? in[(size_t)(k0 + ty + i) * N + n] : 0.0f;
    }
    __syncthreads();
#pragma unroll
    for (int i = 0; i < 32; i += 8) {
        out[(size_t)(n0 + ty + i) * K + (k0 + tx)] = f2b(tile[tx][ty + i]);
    }
}

// ---------- concat bias [bq|bk|bv|bbeta|0pad] -> 3200 ----------
__global__ void build_bias_k(const float* __restrict__ bq, const float* __restrict__ bk,
                             const float* __restrict__ bv, const float* __restrict__ bb,
                             float* __restrict__ outb)
{
    int i = blockIdx.x * 256 + threadIdx.x;
    if (i >= 3200) return;
    float v = 0.f;
    if (i < 1024)      v = bq[i];
    else if (i < 2048) v = bk[i - 1024];
    else if (i < 3072) v = bv[i - 2048];
    else if (i < 3088) v = bb[i - 3072];
    outb[i] = v;
}

// ---------- rmsnorm (rows of 1024) + cast to bf16 ----------
__global__ __launch_bounds__(256) void rmsnorm_cast_k(
    const float* __restrict__ x, const float* __restrict__ scale,
    unsigned short* __restrict__ out)
{
    const int row = blockIdx.x;
    const int t = threadIdx.x;
    const float4 v = *(const float4*)(x + (size_t)row * 1024 + t * 4);
    float ss = v.x * v.x + v.y * v.y + v.z * v.z + v.w * v.w;
#pragma unroll
    for (int off = 1; off < 64; off <<= 1) ss += __shfl_xor(ss, off);
    __shared__ float wsum[4];
    if ((t & 63) == 0) wsum[t >> 6] = ss;
    __syncthreads();
    const float tot = wsum[0] + wsum[1] + wsum[2] + wsum[3];
    const float inv = rsqrtf(tot * (1.0f / 1024.0f) + 1e-6f);
    const float4 sc = *(const float4*)(scale + t * 4);
    uint lo = (uint)f2b(v.x * inv * sc.x) | ((uint)f2b(v.y * inv * sc.y) << 16);
    uint hi = (uint)f2b(v.z * inv * sc.z) | ((uint)f2b(v.w * inv * sc.w) << 16);
    uint2 pkd; pkd.x = lo; pkd.y = hi;
    *(uint2*)(out + (size_t)row * 1024 + t * 4) = pkd;
}

// ---------- GEMM: C[M,N] = A[M,K](bf16) * BT[N,K](bf16)^T ----------
// m97 structure + XOR bank-conflict swizzle + vectorized bf16 epilogue.
// MODE 0: C=f32 +bias   MODE 1: C=f32 +bias+add   MODE 2: C=bf16 gelu(+bias)   MODE 3: C=bf16 +bias
template <int MODE>
__global__ __launch_bounds__(256) void gemm_bt(
    const unsigned short* __restrict__ A, const unsigned short* __restrict__ BT,
    const float* __restrict__ bias, const float* __restrict__ add,
    void* __restrict__ Cout, int N, int K)
{
    __shared__ unsigned short As[128 * 32];   // 8 KB
    __shared__ unsigned short Bs[128 * 32];   // 8 KB
    const int tid = threadIdx.x;
    const int wid = tid >> 6;
    const int lane = tid & 63;
    const int m0 = blockIdx.x * 128;
    const int n0 = blockIdx.y * 128;

    const int lrow = lane >> 2;                              // 0..15
    // staging: lane loads global k-chunk (lane&3)^sel(row), sel(row)=((row)>>1)&3 = (lane>>3)&3
    const int lkw = (((lane & 3) ^ ((lane >> 3) & 3))) * 8;  // swizzled ushort offset in 32-wide k row

    const unsigned short* Ag0 = A + (size_t)(m0 + wid * 16 + lrow) * K + lkw;
    const unsigned short* Ag1 = A + (size_t)(m0 + wid * 16 + 64 + lrow) * K + lkw;
    const unsigned short* Bg0 = BT + (size_t)(n0 + wid * 16 + lrow) * K + lkw;
    const unsigned short* Bg1 = BT + (size_t)(n0 + wid * 16 + 64 + lrow) * K + lkw;
    unsigned short* As0 = &As[(wid * 16) * 32];
    unsigned short* As1 = &As[(wid * 16 + 64) * 32];
    unsigned short* Bs0 = &Bs[(wid * 16) * 32];
    unsigned short* Bs1 = &Bs[(wid * 16 + 64) * 32];

    f32x4 acc[4][4];
#pragma unroll
    for (int i = 0; i < 4; i++)
#pragma unroll
        for (int j = 0; j < 4; j++) acc[i][j] = (f32x4)0.f;

    const int wm = (wid & 1) * 64;
    const int wn = (wid >> 1) * 64;
    const int l16 = lane & 15;
    const int quad = lane >> 4;
    // frag read: logical chunk quad lives at physical chunk quad^((l16>>1)&3)
    const int koffs = (quad ^ ((l16 >> 1) & 3)) * 8;

    for (int k0 = 0; k0 < K; k0 += 32) {
        async_cp16(Ag0 + k0, As0);
        async_cp16(Ag1 + k0, As1);
        async_cp16(Bg0 + k0, Bs0);
        async_cp16(Bg1 + k0, Bs1);
        __syncthreads();
        bf16x8 af[4], bfv[4];
#pragma unroll
        for (int i = 0; i < 4; i++) af[i] = *(const bf16x8*)&As[(wm + i * 16 + l16) * 32 + koffs];
#pragma unroll
        for (int j = 0; j < 4; j++) bfv[j] = *(const bf16x8*)&Bs[(wn + j * 16 + l16) * 32 + koffs];
#pragma unroll
        for (int i = 0; i < 4; i++)
#pragma unroll
            for (int j = 0; j < 4; j++)
                acc[i][j] = __builtin_amdgcn_mfma_f32_16x16x32_bf16(af[i], bfv[j], acc[i][j], 0, 0, 0);
        __syncthreads();
    }

    if (MODE == 2 || MODE == 3) {
        // vectorized bf16 epilogue: LDS roundtrip, col-major stride-17 (conflict-free)
        float* ep = ((wid & 2) ? (float*)Bs : (float*)As) + (wid & 1) * 1024;  // 544 used of 1024
        const int rr = lane >> 2, cg = lane & 3;
        unsigned short* Cu = (unsigned short*)Cout;
#pragma unroll
        for (int i = 0; i < 4; i++) {
#pragma unroll
            for (int p = 0; p < 2; p++) {
#pragma unroll
                for (int jj = 0; jj < 2; jj++) {
                    const int j = 2 * p + jj;
                    const float bv = bias[n0 + wn + j * 16 + l16];
#pragma unroll
                    for (int r = 0; r < 4; r++) {
                        float v = acc[i][j][r] + bv;
                        if (MODE == 2) v = gelu_f(v);
                        ep[(jj * 16 + l16) * 17 + quad * 4 + r] = v;
                    }
                }
                __syncthreads();
                uint4 pk;
                float f[8];
#pragma unroll
                for (int m = 0; m < 8; m++) f[m] = ep[(cg * 8 + m) * 17 + rr];
                pk.x = packbf2(f[0], f[1]); pk.y = packbf2(f[2], f[3]);
                pk.z = packbf2(f[4], f[5]); pk.w = packbf2(f[6], f[7]);
                *(uint4*)(Cu + (size_t)(m0 + wm + i * 16 + rr) * N + (n0 + wn + p * 32 + cg * 8)) = pk;
                __syncthreads();
            }
        }
    } else {
#pragma unroll
        for (int j = 0; j < 4; j++) {
            const int cg2 = n0 + wn + j * 16 + l16;
            const float bv = bias[cg2];
#pragma unroll
            for (int i = 0; i < 4; i++) {
                const int rg0 = m0 + wm + i * 16 + quad * 4;
#pragma unroll
                for (int r = 0; r < 4; r++) {
                    size_t idx = (size_t)(rg0 + r) * N + cg2;
                    float v = acc[i][j][r] + bv;
                    if (MODE == 1) v += add[idx];
                    ((float*)Cout)[idx] = v;
                }
            }
        }
    }
}

// =====================================================================
// Chunked WY delta-rule scan, chunk L=64 (all bf16 tensors, MFMA prop).
// Tiled global layouts per (bh,ch), flat 4096 ush = 8KB:
//   Wg  : [g_d(8)][t(64)][8]   W[t][d]
//   KTg : [g_t(8)][d(64)][8]   Kn[t][d] transposed
//   ZTg : [g_t(8)][j(64)][8]   Z[t][j] transposed
//   Sall: [d(64)][j(64)]       chunk-start S (S[j][d] stored d-major)
//   Yg  : [t(64)][j(64)]       Y row-major
// =====================================================================

// ---------- prep: normalize k in place (bf16 qkv), build A, solve W,Z, emit tiled layouts ----------
__global__ __launch_bounds__(256) void gdn_prep(
    unsigned short* __restrict__ qkv, unsigned short* __restrict__ Wg,
    unsigned short* __restrict__ ZTg, unsigned short* __restrict__ KTg)
{
    const int chunk = blockIdx.x, bh = blockIdx.y;
    const int b = bh >> 4, h = bh & 15;
    __shared__ float Ks[64 * 68];
    __shared__ float Ws[64 * 65];
    __shared__ float Zs[64 * 65];
    __shared__ float Asl[64 * 65];
    __shared__ float bs[64];
    const int tid = threadIdx.x;
    const int t = tid >> 2, c = tid & 3;
    unsigned short* rowp = qkv + (size_t)(b * 2048 + chunk * 64 + t) * 3200;

    // phase 1a: load k slice (bf16), row norm, write Kn to LDS + back to global
    float kn[16];
    {
        uint4 ka = *(const uint4*)(rowp + 1024 + h * 64 + 16 * c);
        uint4 kb = *(const uint4*)(rowp + 1024 + h * 64 + 16 * c + 8);
        dec8(ka, kn); dec8(kb, kn + 8);
    }
    float ss = 0.f;
#pragma unroll
    for (int j = 0; j < 16; j++) ss += kn[j] * kn[j];
    ss = quad_sum(ss);
    const float inv = 1.f / (sqrtf(ss) + 1e-6f);
#pragma unroll
    for (int j = 0; j < 16; j++) kn[j] *= inv;
#pragma unroll
    for (int j = 0; j < 16; j++) Ks[t * 68 + 16 * c + j] = kn[j];
    {
        uint4 p0, p1;
        p0.x = packbf2(kn[0], kn[1]);  p0.y = packbf2(kn[2], kn[3]);
        p0.z = packbf2(kn[4], kn[5]);  p0.w = packbf2(kn[6], kn[7]);
        p1.x = packbf2(kn[8], kn[9]);  p1.y = packbf2(kn[10], kn[11]);
        p1.z = packbf2(kn[12], kn[13]); p1.w = packbf2(kn[14], kn[15]);
        *(uint4*)(rowp + 1024 + h * 64 + 16 * c) = p0;
        *(uint4*)(rowp + 1024 + h * 64 + 16 * c + 8) = p1;
    }
    if (c == 0) bs[t] = 1.f / (1.f + __expf(-b2f(rowp[3072 + h])));
    __syncthreads();

    // phase 1b: RHS: W = beta*Kn, Z = beta*V
    const float beta = bs[t];
#pragma unroll
    for (int j = 0; j < 16; j++) Ws[t * 65 + 16 * c + j] = beta * kn[j];
    {
        float vv[16];
        uint4 va = *(const uint4*)(rowp + 2048 + h * 64 + 16 * c);
        uint4 vb = *(const uint4*)(rowp + 2048 + h * 64 + 16 * c + 8);
        dec8(va, vv); dec8(vb, vv + 8);
#pragma unroll
        for (int j = 0; j < 16; j++) Zs[t * 65 + 16 * c + j] = beta * vv[j];
    }
    __syncthreads();

    // phase 2: A = strictly_lower(diag(beta) Kn Kn^T); 4x4 tile per thread
    {
        const int tt = tid >> 4, sx = tid & 15;
        float dm[4][4];
#pragma unroll
        for (int i = 0; i < 4; i++)
#pragma unroll
            for (int j = 0; j < 4; j++) dm[i][j] = 0.f;
        for (int d = 0; d < 64; d++) {
            float kt[4], ksv[4];
#pragma unroll
            for (int i = 0; i < 4; i++) kt[i] = Ks[(4 * tt + i) * 68 + d];
#pragma unroll
            for (int j = 0; j < 4; j++) ksv[j] = Ks[(4 * sx + j) * 68 + d];
#pragma unroll
            for (int i = 0; i < 4; i++)
#pragma unroll
                for (int j = 0; j < 4; j++) dm[i][j] += kt[i] * ksv[j];
        }
#pragma unroll
        for (int i = 0; i < 4; i++)
#pragma unroll
            for (int j = 0; j < 4; j++) {
                int T = 4 * tt + i, S_ = 4 * sx + j;
                Asl[T * 65 + S_] = (S_ < T) ? bs[T] * dm[i][j] : 0.f;
            }
    }
    __syncthreads();

    // phase 3: blocked forward substitution (I+A)X = RHS for W and Z
    {
        const int wid = tid >> 6, lane = tid & 63;  // lane = d
        for (int qi = 0; qi < 4; qi++) {
            if (qi > 0) {
                const int tb = qi * 16 + wid * 4;
                float aw[4], az[4];
#pragma unroll
                for (int i = 0; i < 4; i++) { aw[i] = Ws[(tb + i) * 65 + lane]; az[i] = Zs[(tb + i) * 65 + lane]; }
                for (int s = 0; s < qi * 16; s++) {
                    float wsv = Ws[s * 65 + lane], zsv = Zs[s * 65 + lane];
#pragma unroll
                    for (int i = 0; i < 4; i++) {
                        float a = Asl[(tb + i) * 65 + s];
                        aw[i] -= a * wsv; az[i] -= a * zsv;
                    }
                }
#pragma unroll
                for (int i = 0; i < 4; i++) { Ws[(tb + i) * 65 + lane] = aw[i]; Zs[(tb + i) * 65 + lane] = az[i]; }
            }
            __syncthreads();
            if (wid == 0) {
                for (int T = qi * 16; T < qi * 16 + 16; T++) {
                    float a_ = Ws[T * 65 + lane];
                    for (int s = qi * 16; s < T; s++) a_ -= Asl[T * 65 + s] * Ws[s * 65 + lane];
                    Ws[T * 65 + lane] = a_;
                }
            } else if (wid == 1) {
                for (int T = qi * 16; T < qi * 16 + 16; T++) {
                    float a_ = Zs[T * 65 + lane];
                    for (int s = qi * 16; s < T; s++) a_ -= Asl[T * 65 + s] * Zs[s * 65 + lane];
                    Zs[T * 65 + lane] = a_;
                }
            }
            __syncthreads();
        }
    }

    // phase 4: tiled bf16 outputs
    const size_t cbase = ((size_t)bh * 32 + chunk) * 4096;
    // Wg [g_d][t][8] from Ws[t][d]
    {
#pragma unroll
        for (int half = 0; half < 2; half++) {
            uint4 w4;
            w4.x = packbf2(Ws[t * 65 + 16 * c + half * 8 + 0], Ws[t * 65 + 16 * c + half * 8 + 1]);
            w4.y = packbf2(Ws[t * 65 + 16 * c + half * 8 + 2], Ws[t * 65 + 16 * c + half * 8 + 3]);
            w4.z = packbf2(Ws[t * 65 + 16 * c + half * 8 + 4], Ws[t * 65 + 16 * c + half * 8 + 5]);
            w4.w = packbf2(Ws[t * 65 + 16 * c + half * 8 + 6], Ws[t * 65 + 16 * c + half * 8 + 7]);
            *(uint4*)(Wg + cbase + (size_t)((2 * c + half) * 64 + t) * 8) = w4;
        }
    }
    // ZTg [g_t][j][8] from Zs[t][j]  (thread: jj = tid>>2, tq = tid&3)
    {
        const int jj = tid >> 2, tq = tid & 3;
#pragma unroll
        for (int half = 0; half < 2; half++) {
            uint4 z4;
            int i0 = half * 8;
            z4.x = packbf2(Zs[(16 * tq + i0 + 0) * 65 + jj], Zs[(16 * tq + i0 + 1) * 65 + jj]);
            z4.y = packbf2(Zs[(16 * tq + i0 + 2) * 65 + jj], Zs[(16 * tq + i0 + 3) * 65 + jj]);
            z4.z = packbf2(Zs[(16 * tq + i0 + 4) * 65 + jj], Zs[(16 * tq + i0 + 5) * 65 + jj]);
            z4.w = packbf2(Zs[(16 * tq + i0 + 6) * 65 + jj], Zs[(16 * tq + i0 + 7) * 65 + jj]);
            *(uint4*)(ZTg + cbase + (size_t)((2 * tq + half) * 64 + jj) * 8) = z4;
        }
    }
    // KTg [g_t][d][8] from Ks[t][d]
    {
        const int dd = tid >> 2, tq = tid & 3;
#pragma unroll
        for (int half = 0; half < 2; half++) {
            uint4 k4;
            int i0 = half * 8;
            k4.x = packbf2(Ks[(16 * tq + i0 + 0) * 68 + dd], Ks[(16 * tq + i0 + 1) * 68 + dd]);
            k4.y = packbf2(Ks[(16 * tq + i0 + 2) * 68 + dd], Ks[(16 * tq + i0 + 3) * 68 + dd]);
            k4.z = packbf2(Ks[(16 * tq + i0 + 4) * 68 + dd], Ks[(16 * tq + i0 + 5) * 68 + dd]);
            k4.w = packbf2(Ks[(16 * tq + i0 + 6) * 68 + dd], Ks[(16 * tq + i0 + 7) * 68 + dd]);
            *(uint4*)(KTg + cbase + (size_t)((2 * tq + half) * 64 + dd) * 8) = k4;
        }
    }
}

// ---------- prop (MFMA): 64 blocks (bh), 4 waves; wave w owns j-rows 16w..16w+15 ----------
__global__ __launch_bounds__(256, 1) void gdn_prop_mfma(
    const unsigned short* __restrict__ Wg, const unsigned short* __restrict__ KTg,
    const unsigned short* __restrict__ ZTg, unsigned short* __restrict__ Sall,
    unsigned short* __restrict__ Yg)
{
    const int bh = blockIdx.x;
    __shared__ unsigned short WbU[4096];   // [g_d][t][8]
    __shared__ unsigned short KTbU[4096];  // [g_t][d][8]
    __shared__ unsigned short ZTbU[4096];  // [g_t][j][8]; overwritten by Y in place
    __shared__ unsigned short SbU[4096];   // [g_d][j][8]
    const int tid = threadIdx.x;
    const int wid = tid >> 6;
    const int lane = tid & 63;
    const int l16 = lane & 15, quad = lane >> 4;

    f32x4 Sacc[4];   // (j=16wid+quad*4+r, d=16dt+l16)
#pragma unroll
    for (int dt = 0; dt < 4; dt++) Sacc[dt] = (f32x4)0.f;

    for (int ch = 0; ch < 32; ch++) {
        const size_t cbase = ((size_t)bh * 32 + ch) * 4096;
#pragma unroll
        for (int p = 0; p < 2; p++) {
            const int n = wid * 2 + p;
            async_cp16(Wg + cbase + n * 512 + lane * 8, &WbU[n * 512]);
            async_cp16(KTg + cbase + n * 512 + lane * 8, &KTbU[n * 512]);
            async_cp16(ZTg + cbase + n * 512 + lane * 8, &ZTbU[n * 512]);
        }
#pragma unroll
        for (int dt = 0; dt < 4; dt++) {
#pragma unroll
            for (int r = 0; r < 4; r++) {
                const int j = wid * 16 + quad * 4 + r;
                SbU[((2 * dt + (l16 >> 3)) * 64 + j) * 8 + (l16 & 7)] = f2b(Sacc[dt][r]);
            }
            const int d = dt * 16 + l16;
            uint2 sp;
            sp.x = packbf2(Sacc[dt][0], Sacc[dt][1]);
            sp.y = packbf2(Sacc[dt][2], Sacc[dt][3]);
            *(uint2*)(Sall + cbase + d * 64 + wid * 16 + quad * 4) = sp;
        }
        __syncthreads();

        // MFMA1': T1^T[j][t] = sum_d Sb[j][d] * Wb[t][d]
        f32x4 t1[4];
#pragma unroll
        for (int tt = 0; tt < 4; tt++) t1[tt] = (f32x4)0.f;
#pragma unroll
        for (int kh = 0; kh < 2; kh++) {
            const int g = kh * 4 + quad;
            bf16x8 afr = *(const bf16x8*)&SbU[(g * 64 + wid * 16 + l16) * 8];
#pragma unroll
            for (int tt = 0; tt < 4; tt++) {
                bf16x8 bfr = *(const bf16x8*)&WbU[(g * 64 + tt * 16 + l16) * 8];
                t1[tt] = __builtin_amdgcn_mfma_f32_16x16x32_bf16(afr, bfr, t1[tt], 0, 0, 0);
            }
        }
        // Y = Z - T1: in-place into ZTb (as YT[j][t]) + packed store to Yg[t][j]
#pragma unroll
        for (int tt = 0; tt < 4; tt++) {
            const int t = tt * 16 + l16;
            const int gb = (t >> 3) * 64;
            unsigned short ybf[4];
#pragma unroll
            for (int r = 0; r < 4; r++) {
                const int j = wid * 16 + quad * 4 + r;
                const float z = b2f(ZTbU[(gb + j) * 8 + (t & 7)]);
                ybf[r] = f2b(z - t1[tt][r]);
            }
#pragma unroll
            for (int r = 0; r < 4; r++) {
                const int j = wid * 16 + quad * 4 + r;
                ZTbU[(gb + j) * 8 + (t & 7)] = ybf[r];
            }
            uint2 yp;
            yp.x = (uint)ybf[0] | ((uint)ybf[1] << 16);
            yp.y = (uint)ybf[2] | ((uint)ybf[3] << 16);
            *(uint2*)(Yg + cbase + t * 64 + wid * 16 + quad * 4) = yp;
        }
        // MFMA2: S[j][d] += sum_t YT[j][t] * KT[d][t]
#pragma unroll
        for (int kh = 0; kh < 2; kh++) {
            const int g = kh * 4 + quad;
            bf16x8 afr = *(const bf16x8*)&ZTbU[(g * 64 + wid * 16 + l16) * 8];
#pragma unroll
            for (int dt = 0; dt < 4; dt++) {
                bf16x8 bfr = *(const bf16x8*)&KTbU[(g * 64 + dt * 16 + l16) * 8];
                Sacc[dt] = __builtin_amdgcn_mfma_f32_16x16x32_bf16(afr, bfr, Sacc[dt], 0, 0, 0);
            }
        }
        __syncthreads();
    }
}

// ---------- output: per (bh, chunk): O = Q S_c^T + tril(Q Kn^T) Y ----------
__global__ __launch_bounds__(256) void gdn_out(
    const unsigned short* __restrict__ qkv, const unsigned short* __restrict__ Yg,
    const unsigned short* __restrict__ Sall, unsigned short* __restrict__ attn)
{
    const int chunk = blockIdx.x, bh = blockIdx.y;
    const int b = bh >> 4, h = bh & 15;
    __shared__ float Qf[64 * 68];
    __shared__ float SfT[64 * 68];   // [d][j]
    __shared__ float Ms[64 * 65];
    __shared__ uint Kp[64 * 33];
    __shared__ uint Yp[64 * 34];
    const int tid = threadIdx.x;
    const int t = tid >> 2, c = tid & 3;
    const size_t cbase = ((size_t)bh * 32 + chunk) * 4096;

    // stage
    {
        const unsigned short* rowp = qkv + (size_t)(b * 2048 + chunk * 64 + t) * 3200;
        float qv[16];
        uint4 qa = *(const uint4*)(rowp + h * 64 + 16 * c);
        uint4 qb = *(const uint4*)(rowp + h * 64 + 16 * c + 8);
        dec8(qa, qv); dec8(qb, qv + 8);
#pragma unroll
        for (int m = 0; m < 16; m++) Qf[t * 68 + 16 * c + m] = qv[m];
        uint4 ka = *(const uint4*)(rowp + 1024 + h * 64 + 16 * c);
        uint4 kb = *(const uint4*)(rowp + 1024 + h * 64 + 16 * c + 8);
        Kp[t * 33 + 8 * c + 0] = ka.x; Kp[t * 33 + 8 * c + 1] = ka.y;
        Kp[t * 33 + 8 * c + 2] = ka.z; Kp[t * 33 + 8 * c + 3] = ka.w;
        Kp[t * 33 + 8 * c + 4] = kb.x; Kp[t * 33 + 8 * c + 5] = kb.y;
        Kp[t * 33 + 8 * c + 6] = kb.z; Kp[t * 33 + 8 * c + 7] = kb.w;
        const unsigned short* yrow = Yg + cbase + t * 64 + 16 * c;
        uint4 ya = *(const uint4*)yrow;
        uint4 yb = *(const uint4*)(yrow + 8);
        Yp[t * 34 + 8 * c + 0] = ya.x; Yp[t * 34 + 8 * c + 1] = ya.y;
        Yp[t * 34 + 8 * c + 2] = ya.z; Yp[t * 34 + 8 * c + 3] = ya.w;
        Yp[t * 34 + 8 * c + 4] = yb.x; Yp[t * 34 + 8 * c + 5] = yb.y;
        Yp[t * 34 + 8 * c + 6] = yb.z; Yp[t * 34 + 8 * c + 7] = yb.w;
        const unsigned short* srow = Sall + cbase + t * 64 + 16 * c; // t = d row
        float sv[16];
        uint4 sa = *(const uint4*)srow;
        uint4 sb = *(const uint4*)(srow + 8);
        dec8(sa, sv); dec8(sb, sv + 8);
#pragma unroll
        for (int m = 0; m < 16; m++) SfT[t * 68 + 16 * c + m] = sv[m];
    }
    __syncthreads();

    const int tt = tid >> 4, sx = tid & 15;
    // M = tril(Q Kn^T) incl diag
    {
        float dm[4][4];
#pragma unroll
        for (int i = 0; i < 4; i++)
#pragma unroll
            for (int j = 0; j < 4; j++) dm[i][j] = 0.f;
        for (int p = 0; p < 32; p++) {
            float q0[4], q1[4];
#pragma unroll
            for (int i = 0; i < 4; i++) {
                q0[i] = Qf[(4 * tt + i) * 68 + 2 * p];
                q1[i] = Qf[(4 * tt + i) * 68 + 2 * p + 1];
            }
#pragma unroll
            for (int j = 0; j < 4; j++) {
                uint kp = Kp[(4 * sx + j) * 33 + p];
                float kk0 = b2f_lo(kp), kk1 = b2f_hi(kp);
#pragma unroll
                for (int i = 0; i < 4; i++) dm[i][j] += q0[i] * kk0 + q1[i] * kk1;
            }
        }
#pragma unroll
        for (int i = 0; i < 4; i++)
#pragma unroll
            for (int j = 0; j < 4; j++) {
                int T = 4 * tt + i, S_ = 4 * sx + j;
                Ms[T * 65 + S_] = (S_ <= T) ? dm[i][j] : 0.f;
            }
    }
    __syncthreads();

    // O[4tt..][4sx..]: part1 Q S_c^T + part2 M Y
    {
        float o[4][4];
#pragma unroll
        for (int i = 0; i < 4; i++)
#pragma unroll
            for (int j = 0; j < 4; j++) o[i][j] = 0.f;
        for (int d = 0; d < 64; d++) {
            float qv[4];
#pragma unroll
            for (int i = 0; i < 4; i++) qv[i] = Qf[(4 * tt + i) * 68 + d];
#pragma unroll
            for (int j = 0; j < 4; j++) {
                float sv = SfT[d * 68 + 4 * sx + j];
#pragma unroll
                for (int i = 0; i < 4; i++) o[i][j] += qv[i] * sv;
            }
        }
        for (int s = 0; s < 64; s++) {
            float mv[4];
#pragma unroll
            for (int i = 0; i < 4; i++) mv[i] = Ms[(4 * tt + i) * 65 + s];
            uint2 yp2 = *(const uint2*)&Yp[s * 34 + 2 * sx];
            float yv0 = b2f_lo(yp2.x), yv1 = b2f_hi(yp2.x), yv2 = b2f_lo(yp2.y), yv3 = b2f_hi(yp2.y);
#pragma unroll
            for (int i = 0; i < 4; i++) {
                o[i][0] += mv[i] * yv0; o[i][1] += mv[i] * yv1;
                o[i][2] += mv[i] * yv2; o[i][3] += mv[i] * yv3;
            }
        }
#pragma unroll
        for (int i = 0; i < 4; i++) {
            uint2 op; op.x = packbf2(o[i][0], o[i][1]); op.y = packbf2(o[i][2], o[i][3]);
            *(uint2*)(attn + (size_t)(b * 2048 + chunk * 64 + 4 * tt + i) * 1024 + h * 64 + 4 * sx) = op;
        }
    }
}

// ---------- workspace layout (bytes) ----------
static constexpr size_t OFF_H     = 0;                          // 16,777,216  hbuf bf16 / Sall bf16
static constexpr size_t OFF_WQKVT = OFF_H + 16777216;           //  6,553,600
static constexpr size_t OFF_WOT   = OFF_WQKVT + 6553600;        //  2,097,152
static constexpr size_t OFF_W1T   = OFF_WOT + 2097152;          //  8,388,608
static constexpr size_t OFF_W2T   = OFF_W1T + 8388608;          //  8,388,608
static constexpr size_t OFF_BIAS  = OFF_W2T + 8388608;          //     16,384
static constexpr size_t OFF_QKV   = OFF_BIAS + 16384;           // 67,108,864  qkv bf16 / gbuf bf16
static constexpr size_t OFF_ATTN  = OFF_QKV + 67108864;         // 16,777,216  bf16
static constexpr size_t OFF_Y1    = OFF_ATTN + 16777216;        // 33,554,432  y1 f32 / (ZTg+KTg bf16)
static constexpr size_t OFF_WG    = OFF_Y1 + 33554432;          // 16,777,216  Wg bf16
static constexpr size_t OFF_YG    = OFF_WG + 16777216;          // 16,777,216  Yg bf16

extern "C" void kernel_launch(void* const* d_in, const int* in_sizes, int n_in,
                              void* d_out, int out_size, void* d_ws, size_t ws_size,
                              hipStream_t stream)
{
    const float* x     = (const float*)d_in[0];
    const float* wq    = (const float*)d_in[1];
    const float* bq    = (const float*)d_in[2];
    const float* wk    = (const float*)d_in[3];
    const float* bk    = (const float*)d_in[4];
    const float* wv    = (const float*)d_in[5];
    const float* bv    = (const float*)d_in[6];
    const float* wbeta = (const float*)d_in[7];
    const float* bbeta = (const float*)d_in[8];
    const float* wo    = (const float*)d_in[9];
    const float* bo    = (const float*)d_in[10];
    const float* w1    = (const float*)d_in[11];
    const float* b1    = (const float*)d_in[12];
    const float* w2    = (const float*)d_in[13];
    const float* b2    = (const float*)d_in[14];
    const float* ln1   = (const float*)d_in[15];
    const float* ln2   = (const float*)d_in[16];

    char* ws = (char*)d_ws;
    unsigned short* hbuf  = (unsigned short*)(ws + OFF_H);
    unsigned short* Sall  = (unsigned short*)(ws + OFF_H);
    unsigned short* wqkvT = (unsigned short*)(ws + OFF_WQKVT);
    unsigned short* woT   = (unsigned short*)(ws + OFF_WOT);
    unsigned short* w1T   = (unsigned short*)(ws + OFF_W1T);
    unsigned short* w2T   = (unsigned short*)(ws + OFF_W2T);
    float*          biasc = (float*)(ws + OFF_BIAS);
    unsigned short* qkvU  = (unsigned short*)(ws + OFF_QKV);
    unsigned short* gbuf  = (unsigned short*)(ws + OFF_QKV);
    unsigned short* attn  = (unsigned short*)(ws + OFF_ATTN);
    float*          y1    = (float*)(ws + OFF_Y1);
    unsigned short* ZTg   = (unsigned short*)(ws + OFF_Y1);
    unsigned short* KTg   = (unsigned short*)(ws + OFF_Y1 + 16777216);
    unsigned short* Wg    = (unsigned short*)(ws + OFF_WG);
    unsigned short* Yg    = (unsigned short*)(ws + OFF_YG);
    float*          out   = (float*)d_out;

    // weight transpose+cast (B^T bf16 operands)
    transpose_cast_k<<<dim3(32, 32), 256, 0, stream>>>(wq, wqkvT,               1024, 1024);
    transpose_cast_k<<<dim3(32, 32), 256, 0, stream>>>(wk, wqkvT + 1024 * 1024, 1024, 1024);
    transpose_cast_k<<<dim3(32, 32), 256, 0, stream>>>(wv, wqkvT + 2048 * 1024, 1024, 1024);
    transpose_cast_k<<<dim3(32, 4),  256, 0, stream>>>(wbeta, wqkvT + 3072 * 1024, 1024, 16);
    transpose_cast_k<<<dim3(32, 32), 256, 0, stream>>>(wo, woT, 1024, 1024);
    transpose_cast_k<<<dim3(32, 128), 256, 0, stream>>>(w1, w1T, 1024, 4096);
    transpose_cast_k<<<dim3(128, 32), 256, 0, stream>>>(w2, w2T, 4096, 1024);
    build_bias_k<<<13, 256, 0, stream>>>(bq, bk, bv, bbeta, biasc);

    // layer
    rmsnorm_cast_k<<<8192, 256, 0, stream>>>(x, ln1, hbuf);
    gemm_bt<3><<<dim3(64, 25), 256, 0, stream>>>(hbuf, wqkvT, biasc, nullptr, qkvU, 3200, 1024);
    gdn_prep<<<dim3(32, 64), 256, 0, stream>>>(qkvU, Wg, ZTg, KTg);
    gdn_prop_mfma<<<64, 256, 0, stream>>>(Wg, KTg, ZTg, Sall, Yg);
    gdn_out<<<dim3(32, 64), 256, 0, stream>>>(qkvU, Yg, Sall, attn);
    gemm_bt<1><<<dim3(64, 8), 256, 0, stream>>>(attn, woT, bo, x, y1, 1024, 1024);
    rmsnorm_cast_k<<<8192, 256, 0, stream>>>(y1, ln2, hbuf);
    gemm_bt<2><<<dim3(64, 32), 256, 0, stream>>>(hbuf, w1T, b1, nullptr, gbuf, 4096, 1024);
    gemm_bt<1><<<dim3(64, 8), 256, 0, stream>>>(gbuf, w2T, b2, y1, out, 1024, 4096);
}